// Round 4
// baseline (3436.492 us; speedup 1.0000x reference)
//
#include <hip/hip_runtime.h>
#include <math.h>

#define BATCH 4
#define NQ 2048
#define NK 2048
#define DQ 1024
#define NHEADS 8
#define DHEAD 64
#define INNER (NHEADS*DHEAD)     // 512
#define NROWS (BATCH*NHEADS*NQ)  // 65536
#define CAND_MAX 128

// ---------------------------------------------------------------------------
// f64-accumulate projection GEMM (fp32 in): C64[bh][n][d] scatter.
// ---------------------------------------------------------------------------
__global__ __launch_bounds__(256) void gemm_f64_proj(
    const float* __restrict__ A, const float* __restrict__ Bm,
    int ldb, int bcoloff, double* __restrict__ C64)
{
  __shared__ double As[16*66];  // [k][m]
  __shared__ double Bs[16*66];  // [k][n]
  const int t  = threadIdx.x;
  const int tx = t & 15, ty = t >> 4;
  const int n0 = blockIdx.x * 64, m0 = blockIdx.y * 64;
  double acc[4][4] = {};

  for (int kt = 0; kt < DQ; kt += 16) {
    int m  = t >> 2;
    int c4 = (t & 3) * 4;
    const float4 av = *(const float4*)(A + (size_t)(m0 + m) * DQ + kt + c4);
    int k  = t >> 4;
    int n4 = (t & 15) * 4;
    const float4 bv = *(const float4*)(Bm + (size_t)(kt + k) * ldb + bcoloff + n0 + n4);
    As[(c4+0)*66 + m] = (double)av.x;
    As[(c4+1)*66 + m] = (double)av.y;
    As[(c4+2)*66 + m] = (double)av.z;
    As[(c4+3)*66 + m] = (double)av.w;
    Bs[k*66 + n4+0] = (double)bv.x;
    Bs[k*66 + n4+1] = (double)bv.y;
    Bs[k*66 + n4+2] = (double)bv.z;
    Bs[k*66 + n4+3] = (double)bv.w;
    __syncthreads();
    #pragma unroll
    for (int kk = 0; kk < 16; ++kk) {
      double av_[4], bv_[4];
      #pragma unroll
      for (int i = 0; i < 4; ++i) { av_[i] = As[kk*66 + ty*4+i]; bv_[i] = Bs[kk*66 + tx*4+i]; }
      #pragma unroll
      for (int i = 0; i < 4; ++i)
        #pragma unroll
        for (int j = 0; j < 4; ++j)
          acc[i][j] = fma(av_[i], bv_[j], acc[i][j]);
    }
    __syncthreads();
  }

  #pragma unroll
  for (int i = 0; i < 4; ++i) {
    int r = m0 + ty*4 + i;
    int b = r >> 11, n = r & (NQ - 1);
    #pragma unroll
    for (int j = 0; j < 4; ++j) {
      int cc = n0 + tx*4 + j;
      int h = cc >> 6, d = cc & 63;
      C64[(((size_t)(b*NHEADS + h))*NQ + n)*64 + d] = acc[i][j];
    }
  }
}

// ---------------------------------------------------------------------------
// fp32 GEMM.  MODE 0: +bias, row-major C0[M][N].  MODE 2: scatter V[bh][n][d].
// ---------------------------------------------------------------------------
template<int MODE>
__global__ __launch_bounds__(256) void gemm_f32(
    const float* __restrict__ A, const float* __restrict__ Bm,
    int ldb, int bcoloff, const float* __restrict__ bias,
    float* __restrict__ C0, int M, int N, int K)
{
  __shared__ float As[16*68];
  __shared__ float Bs[16*68];
  const int t  = threadIdx.x;
  const int tx = t & 15, ty = t >> 4;
  const int n0 = blockIdx.x * 64, m0 = blockIdx.y * 64;
  float acc[4][4] = {};

  for (int kt = 0; kt < K; kt += 16) {
    int m  = t >> 2;
    int c4 = (t & 3) * 4;
    const float4 av = *(const float4*)(A + (size_t)(m0 + m) * K + kt + c4);
    As[(c4+0)*68 + m] = av.x;
    As[(c4+1)*68 + m] = av.y;
    As[(c4+2)*68 + m] = av.z;
    As[(c4+3)*68 + m] = av.w;
    int k  = t >> 4;
    int n4 = (t & 15) * 4;
    const float4 bv = *(const float4*)(Bm + (size_t)(kt + k) * ldb + bcoloff + n0 + n4);
    *(float4*)(Bs + k*68 + n4) = bv;
    __syncthreads();
    #pragma unroll
    for (int kk = 0; kk < 16; ++kk) {
      float4 a4 = *(const float4*)(As + kk*68 + ty*4);
      float4 b4 = *(const float4*)(Bs + kk*68 + tx*4);
      float av_[4] = {a4.x, a4.y, a4.z, a4.w};
      float bv_[4] = {b4.x, b4.y, b4.z, b4.w};
      #pragma unroll
      for (int i = 0; i < 4; ++i)
        #pragma unroll
        for (int j = 0; j < 4; ++j)
          acc[i][j] = fmaf(av_[i], bv_[j], acc[i][j]);
    }
    __syncthreads();
  }

  #pragma unroll
  for (int i = 0; i < 4; ++i) {
    int r = m0 + ty*4 + i;
    int b = r >> 11, n = r & (NQ - 1);
    #pragma unroll
    for (int j = 0; j < 4; ++j) {
      int cc = n0 + tx*4 + j;
      if (MODE == 0) {
        C0[(size_t)r * N + cc] = acc[i][j] + bias[cc];
      } else {
        int h = cc >> 6, d = cc & 63;
        C0[(((size_t)(b*NHEADS + h))*NK + n)*64 + d] = acc[i][j];
      }
    }
  }
}

// ---------------------------------------------------------------------------
// Phase A: fp32 scores, exact fp32 kth, margin collect -> candidate lists.
// ---------------------------------------------------------------------------
__global__ __launch_bounds__(256) void attn_phase_a(
    const double* __restrict__ Q64, const double* __restrict__ K64,
    unsigned short* __restrict__ cand, int* __restrict__ cnt,
    const int* __restrict__ topkp)
{
  extern __shared__ float smem[];
  float* S  = smem;                 // 16 * 2050
  float* Qs = smem + 16*2050;       // 16 * 68
  float* Ks = Qs + 16*68;           // 64 * 68

  const int t  = threadIdx.x;
  const int bh = blockIdx.x;
  const int q0 = blockIdx.y * 16;
  const float scale = 0.125f;

  {
    int q  = t >> 4;
    int c4 = (t & 15) * 4;
    const double* src = Q64 + ((size_t)bh*NQ + q0 + q)*64 + c4;
    float4 f; f.x=(float)src[0]; f.y=(float)src[1]; f.z=(float)src[2]; f.w=(float)src[3];
    *(float4*)(Qs + q*68 + c4) = f;
  }

  const int qg2 = (t & 7) * 2;
  const int kg2 = (t >> 3) * 2;

  for (int kc = 0; kc < NK; kc += 64) {
    __syncthreads();
    #pragma unroll
    for (int i = 0; i < 4; ++i) {
      int idx = t + i*256;
      int row = idx >> 4, c4 = (idx & 15) * 4;
      const double* src = K64 + ((size_t)bh*NK + kc + row)*64 + c4;
      float4 f; f.x=(float)src[0]; f.y=(float)src[1]; f.z=(float)src[2]; f.w=(float)src[3];
      *(float4*)(Ks + row*68 + c4) = f;
    }
    __syncthreads();
    float a00=0.f, a01=0.f, a10=0.f, a11=0.f;
    #pragma unroll
    for (int d = 0; d < 64; d += 4) {
      float4 qa = *(const float4*)(Qs + qg2*68 + d);
      float4 qb = *(const float4*)(Qs + (qg2+1)*68 + d);
      float4 ka = *(const float4*)(Ks + kg2*68 + d);
      float4 kb = *(const float4*)(Ks + (kg2+1)*68 + d);
      a00 += qa.x*ka.x + qa.y*ka.y + qa.z*ka.z + qa.w*ka.w;
      a01 += qa.x*kb.x + qa.y*kb.y + qa.z*kb.z + qa.w*kb.w;
      a10 += qb.x*ka.x + qb.y*ka.y + qb.z*ka.z + qb.w*ka.w;
      a11 += qb.x*kb.x + qb.y*kb.y + qb.z*kb.z + qb.w*kb.w;
    }
    S[ qg2   *2050 + kc + kg2  ] = a00 * scale;
    S[ qg2   *2050 + kc + kg2+1] = a01 * scale;
    S[(qg2+1)*2050 + kc + kg2  ] = a10 * scale;
    S[(qg2+1)*2050 + kc + kg2+1] = a11 * scale;
  }
  __syncthreads();

  int kEff = *topkp;
  if (kEff > CAND_MAX) kEff = CAND_MAX;
  if (kEff < 1) kEff = 1;
  const int w = t >> 6, l = t & 63;
  const unsigned long long lmask = (1ull << l) - 1ull;

  for (int qi = 0; qi < 4; ++qi) {
    const int q = w*4 + qi;
    unsigned uv[32];
    #pragma unroll
    for (int c = 0; c < 32; ++c) {
      unsigned bb = __float_as_uint(S[q*2050 + c*64 + l]);
      uv[c] = (bb & 0x80000000u) ? ~bb : (bb | 0x80000000u);
    }
    unsigned lo = 0u, hi = 0xFFFFFFFFu;
    while (lo < hi) {
      unsigned mid = (unsigned)(((unsigned long long)lo + (unsigned long long)hi + 1ull) >> 1);
      int c_ = 0;
      #pragma unroll
      for (int c = 0; c < 32; ++c) c_ += (uv[c] >= mid) ? 1 : 0;
      #pragma unroll
      for (int off = 32; off > 0; off >>= 1) c_ += __shfl_xor(c_, off);
      if (c_ >= kEff) lo = mid; else hi = mid - 1;
    }
    const unsigned uth = lo;
    float skth = __uint_as_float((uth & 0x80000000u) ? (uth & 0x7FFFFFFFu) : ~uth);
    float smarg = skth - 1e-3f;   // margin >> fp32 score noise and blend band
    unsigned b2 = __float_as_uint(smarg);
    unsigned um = (b2 & 0x80000000u) ? ~b2 : (b2 | 0x80000000u);

    const size_t row = (size_t)bh * NQ + q0 + q;
    int base = 0;
    for (int c = 0; c < 32; ++c) {
      bool pred = (uv[c] >= um);
      unsigned long long msk = __ballot(pred);
      if (pred) {
        int pos = base + __popcll(msk & lmask);
        if (pos < CAND_MAX) cand[row*CAND_MAX + pos] = (unsigned short)(c*64 + l);
      }
      base += __popcll(msk);
    }
    if (l == 0) cnt[row] = (base < CAND_MAX) ? base : CAND_MAX;
  }
}

// ---------------------------------------------------------------------------
// Phase B: f64 re-score, exact kth; if 64th-65th gap < 2*DELTA use a linear
// membership ramp (pair memberships sum to 1) instead of a hard cut; softmax
// + PV (fp32 V), write inner.
// ---------------------------------------------------------------------------
__global__ __launch_bounds__(256) void attn_phase_b(
    const double* __restrict__ Q64, const double* __restrict__ K64,
    const float* __restrict__ V32, const unsigned short* __restrict__ cand,
    const int* __restrict__ cnt, float* __restrict__ inner,
    const int* __restrict__ topkp)
{
  const int t = threadIdx.x;
  const int w = t >> 6, l = t & 63;
  const size_t row = (size_t)blockIdx.x * 4 + w;
  const int bh = (int)(row >> 11);
  const int q  = (int)(row & (NQ - 1));
  const unsigned long long lmask = (1ull << l) - 1ull;

  int kEff = *topkp;
  if (kEff > CAND_MAX) kEff = CAND_MAX;
  if (kEff < 1) kEff = 1;
  int m = cnt[row];
  if (kEff > m) kEff = m;

  const double qv = Q64[row*64 + l];
  const double* Kb = K64 + (size_t)bh * NK * 64;
  const float*  Vb = V32 + (size_t)bh * NK * 64;

  int ck[2];
  ck[0] = cand[row*CAND_MAX + l];
  ck[1] = cand[row*CAND_MAX + 64 + l];
  double cs[2] = {-INFINITY, -INFINITY};
  unsigned long long cu[2] = {0ull, 0ull};

  for (int j = 0; j < m; ++j) {
    int c = j >> 6;
    int key = __shfl(ck[c], j & 63);
    double p = qv * Kb[(size_t)key*64 + l];
    #pragma unroll
    for (int off = 1; off < 64; off <<= 1) p += __shfl_xor(p, off);
    double s = p * 0.125;
    if (l == (j & 63)) {
      unsigned long long b = (unsigned long long)__double_as_longlong(s);
      cs[c] = s;
      cu[c] = (b >> 63) ? ~b : (b | 0x8000000000000000ull);
    }
  }

  // exact kth largest u64
  unsigned long long T = 0ull;
  for (int bit = 63; bit >= 0; --bit) {
    unsigned long long cT = T | (1ull << bit);
    int tot = __popcll(__ballot(cu[0] >= cT)) + __popcll(__ballot(cu[1] >= cT));
    if (tot >= kEff) T = cT;
  }
  double s_kth;
  { unsigned long long bb = (T >> 63) ? (T & 0x7FFFFFFFFFFFFFFFull) : ~T;
    s_kth = __longlong_as_double((long long)bb); }

  // first-excluded score (max over cu < T)
  double nx = -INFINITY;
  #pragma unroll
  for (int c = 0; c < 2; ++c) { double v = (cu[c] < T) ? cs[c] : -INFINITY; nx = fmax(nx, v); }
  #pragma unroll
  for (int off = 32; off > 0; off >>= 1) nx = fmax(nx, __shfl_xor(nx, off));

  double smax = fmax(cs[0], cs[1]);
  #pragma unroll
  for (int off = 32; off > 0; off >>= 1) smax = fmax(smax, __shfl_xor(smax, off));

  const double DELTA = 5e-6;   // half-width of ambiguity band (np fp32 noise ~1e-6)
  float wgt[2];
  if (!(s_kth - nx < 2.0*DELTA)) {
    // unambiguous: exact hard top-k, ties by ascending index
    int cgt = __popcll(__ballot(cu[0] > T)) + __popcll(__ballot(cu[1] > T));
    int nEq = kEff - cgt;
    int eqBase = 0;
    #pragma unroll
    for (int c = 0; c < 2; ++c) {
      bool eq = (cu[c] == T);
      unsigned long long eqm = __ballot(eq);
      int er = __popcll(eqm & lmask);
      bool sel = (cu[c] > T) || (eq && (eqBase + er) < nEq);
      eqBase += __popcll(eqm);
      wgt[c] = sel ? (float)exp(cs[c] - smax) : 0.f;
    }
  } else {
    // ambiguous boundary: linear membership ramp centered between kth/(k+1)th
    double cmid = 0.5 * (s_kth + nx);
    #pragma unroll
    for (int c = 0; c < 2; ++c) {
      double mu = 0.5 + (cs[c] - cmid) / (2.0*DELTA);
      mu = fmin(1.0, fmax(0.0, mu));
      wgt[c] = (float)(mu * exp(cs[c] - smax));
    }
  }

  float acc = 0.f, wsum = 0.f;
  for (int j = 0; j < m; ++j) {
    int c = j >> 6;
    float wj = __shfl(wgt[c], j & 63);
    if (wj != 0.f) {
      int key = __shfl(ck[c], j & 63);
      wsum += wj;
      acc = fmaf(wj, Vb[(size_t)key*64 + l], acc);
    }
  }
  int b = bh >> 3, h = bh & 7;
  inner[((size_t)b*NQ + q)*INNER + h*DHEAD + l] = acc / wsum;
}

// ---------------------------------------------------------------------------
extern "C" void kernel_launch(void* const* d_in, const int* in_sizes, int n_in,
                              void* d_out, int out_size, void* d_ws, size_t ws_size,
                              hipStream_t stream)
{
  const float* x    = (const float*)d_in[0];
  const float* ctx  = (const float*)d_in[1];
  const float* Wq   = (const float*)d_in[2];
  const float* Wkv  = (const float*)d_in[3];
  const float* Wout = (const float*)d_in[4];
  const float* bout = (const float*)d_in[5];
  const int*   topk = (const int*)d_in[6];
  float* out = (float*)d_out;

  const size_t SZ = (size_t)BATCH * NHEADS * NQ * DHEAD;  // 4,194,304
  char* p = (char*)d_ws;
  double* Q64   = (double*)p;  p += SZ * sizeof(double);   // 32 MB
  double* K64   = (double*)p;  p += SZ * sizeof(double);   // 32 MB
  float*  V32   = (float*)p;   p += SZ * sizeof(float);    // 16 MB
  float*  inner = (float*)p;   p += SZ * sizeof(float);    // 16 MB
  unsigned short* cand = (unsigned short*)p; p += (size_t)NROWS * CAND_MAX * sizeof(unsigned short); // 16 MB
  int* cnt = (int*)p;

  const int M = BATCH * NQ;  // 8192
  const size_t SMEM = (size_t)(16*2050 + 16*68 + 64*68) * sizeof(float); // 152,960 B
  hipFuncSetAttribute(reinterpret_cast<const void*>(attn_phase_a),
                      hipFuncAttributeMaxDynamicSharedMemorySize, (int)SMEM);

  gemm_f64_proj<<<dim3(INNER/64, M/64), 256, 0, stream>>>(x,   Wq,  INNER,   0,     Q64);
  gemm_f64_proj<<<dim3(INNER/64, M/64), 256, 0, stream>>>(ctx, Wkv, 2*INNER, 0,     K64);
  gemm_f32<2><<<dim3(INNER/64, M/64), 256, 0, stream>>>(ctx, Wkv, 2*INNER, INNER, nullptr, V32, M, INNER, DQ);
  attn_phase_a<<<dim3(BATCH*NHEADS, NQ/16), 256, SMEM, stream>>>(Q64, K64, cand, cnt, topk);
  attn_phase_b<<<dim3(NROWS/4), 256, 0, stream>>>(Q64, K64, V32, cand, cnt, inner, topk);
  gemm_f32<0><<<dim3(DQ/64, M/64), 256, 0, stream>>>(inner, Wout, DQ, 0, bout, out, M, DQ, INNER);
}

// Round 6
// 2287.905 us; speedup vs baseline: 1.5020x; 1.5020x over previous
//
#include <hip/hip_runtime.h>
#include <math.h>

#define BATCH 4
#define NQ 2048
#define NK 2048
#define DQ 1024
#define NHEADS 8
#define DHEAD 64
#define INNER (NHEADS*DHEAD)     // 512
#define NROWS (BATCH*NHEADS*NQ)  // 65536
#define CAND_MAX 128

using frag_ab = __attribute__((ext_vector_type(8))) short;   // 8 bf16
using frag_cd = __attribute__((ext_vector_type(4))) float;   // 4 fp32
using u16x8   = __attribute__((ext_vector_type(8))) unsigned short;

static __device__ __forceinline__ unsigned short f32_to_bf16_rne(float f) {
  unsigned u = __float_as_uint(f);
  u += 0x7FFFu + ((u >> 16) & 1u);
  return (unsigned short)(u >> 16);
}

// ---------------------------------------------------------------------------
// f64-accumulate projection GEMM (fp32 in): C64[bh][n][d] scatter.
// Epilogue also emits bf16 hi/lo split (for MFMA scoring).
// ---------------------------------------------------------------------------
__global__ __launch_bounds__(256) void gemm_f64_proj(
    const float* __restrict__ A, const float* __restrict__ Bm,
    int ldb, int bcoloff, double* __restrict__ C64,
    unsigned short* __restrict__ Hi, unsigned short* __restrict__ Lo)
{
  __shared__ double As[16*66];  // [k][m]
  __shared__ double Bs[16*66];  // [k][n]
  const int t  = threadIdx.x;
  const int tx = t & 15, ty = t >> 4;
  const int n0 = blockIdx.x * 64, m0 = blockIdx.y * 64;
  double acc[4][4] = {};

  for (int kt = 0; kt < DQ; kt += 16) {
    int m  = t >> 2;
    int c4 = (t & 3) * 4;
    const float4 av = *(const float4*)(A + (size_t)(m0 + m) * DQ + kt + c4);
    int k  = t >> 4;
    int n4 = (t & 15) * 4;
    const float4 bv = *(const float4*)(Bm + (size_t)(kt + k) * ldb + bcoloff + n0 + n4);
    As[(c4+0)*66 + m] = (double)av.x;
    As[(c4+1)*66 + m] = (double)av.y;
    As[(c4+2)*66 + m] = (double)av.z;
    As[(c4+3)*66 + m] = (double)av.w;
    Bs[k*66 + n4+0] = (double)bv.x;
    Bs[k*66 + n4+1] = (double)bv.y;
    Bs[k*66 + n4+2] = (double)bv.z;
    Bs[k*66 + n4+3] = (double)bv.w;
    __syncthreads();
    #pragma unroll
    for (int kk = 0; kk < 16; ++kk) {
      double av_[4], bv_[4];
      #pragma unroll
      for (int i = 0; i < 4; ++i) { av_[i] = As[kk*66 + ty*4+i]; bv_[i] = Bs[kk*66 + tx*4+i]; }
      #pragma unroll
      for (int i = 0; i < 4; ++i)
        #pragma unroll
        for (int j = 0; j < 4; ++j)
          acc[i][j] = fma(av_[i], bv_[j], acc[i][j]);
    }
    __syncthreads();
  }

  #pragma unroll
  for (int i = 0; i < 4; ++i) {
    int r = m0 + ty*4 + i;
    int b = r >> 11, n = r & (NQ - 1);
    #pragma unroll
    for (int j = 0; j < 4; ++j) {
      int cc = n0 + tx*4 + j;
      int h = cc >> 6, d = cc & 63;
      size_t idx = (((size_t)(b*NHEADS + h))*NQ + n)*64 + d;
      C64[idx] = acc[i][j];
      float v = (float)acc[i][j];
      unsigned short hb = f32_to_bf16_rne(v);
      float hf = __uint_as_float((unsigned)hb << 16);
      unsigned short lb = f32_to_bf16_rne(v - hf);
      Hi[idx] = hb;
      Lo[idx] = lb;
    }
  }
}

// ---------------------------------------------------------------------------
// fp32 GEMM.  MODE 0: +bias, row-major C0[M][N].  MODE 2: scatter V[bh][n][d].
// ---------------------------------------------------------------------------
template<int MODE>
__global__ __launch_bounds__(256) void gemm_f32(
    const float* __restrict__ A, const float* __restrict__ Bm,
    int ldb, int bcoloff, const float* __restrict__ bias,
    float* __restrict__ C0, int M, int N, int K)
{
  __shared__ float As[16*68];
  __shared__ float Bs[16*68];
  const int t  = threadIdx.x;
  const int tx = t & 15, ty = t >> 4;
  const int n0 = blockIdx.x * 64, m0 = blockIdx.y * 64;
  float acc[4][4] = {};

  for (int kt = 0; kt < K; kt += 16) {
    int m  = t >> 2;
    int c4 = (t & 3) * 4;
    const float4 av = *(const float4*)(A + (size_t)(m0 + m) * K + kt + c4);
    As[(c4+0)*68 + m] = av.x;
    As[(c4+1)*68 + m] = av.y;
    As[(c4+2)*68 + m] = av.z;
    As[(c4+3)*68 + m] = av.w;
    int k  = t >> 4;
    int n4 = (t & 15) * 4;
    const float4 bv = *(const float4*)(Bm + (size_t)(kt + k) * ldb + bcoloff + n0 + n4);
    *(float4*)(Bs + k*68 + n4) = bv;
    __syncthreads();
    #pragma unroll
    for (int kk = 0; kk < 16; ++kk) {
      float4 a4 = *(const float4*)(As + kk*68 + ty*4);
      float4 b4 = *(const float4*)(Bs + kk*68 + tx*4);
      float av_[4] = {a4.x, a4.y, a4.z, a4.w};
      float bv_[4] = {b4.x, b4.y, b4.z, b4.w};
      #pragma unroll
      for (int i = 0; i < 4; ++i)
        #pragma unroll
        for (int j = 0; j < 4; ++j)
          acc[i][j] = fmaf(av_[i], bv_[j], acc[i][j]);
    }
    __syncthreads();
  }

  #pragma unroll
  for (int i = 0; i < 4; ++i) {
    int r = m0 + ty*4 + i;
    int b = r >> 11, n = r & (NQ - 1);
    #pragma unroll
    for (int j = 0; j < 4; ++j) {
      int cc = n0 + tx*4 + j;
      if (MODE == 0) {
        C0[(size_t)r * N + cc] = acc[i][j] + bias[cc];
      } else {
        int h = cc >> 6, d = cc & 63;
        C0[(((size_t)(b*NHEADS + h))*NK + n)*64 + d] = acc[i][j];
      }
    }
  }
}

// ---------------------------------------------------------------------------
// Score GEMM via bf16x3 MFMA: S[bh_local][q][k] = 0.125 * (q . k), fp32.
// Per block: 128q x 128k tile of one (b,h). 4 waves; wave w owns q-rows
// [32w,32w+32). LDS rows padded to 72 bf16 (144 B).
// err(bf16x3) <~ 1e-4 << 1e-3 candidate margin.
// ---------------------------------------------------------------------------
__global__ __launch_bounds__(256) void score_mfma(
    const unsigned short* __restrict__ Qhi, const unsigned short* __restrict__ Qlo,
    const unsigned short* __restrict__ Khi, const unsigned short* __restrict__ Klo,
    float* __restrict__ S, int bh0)
{
  extern __shared__ unsigned short sm[];
  unsigned short* qh = sm;              // 128*72
  unsigned short* ql = qh + 128*72;
  unsigned short* kh = ql + 128*72;
  unsigned short* kl = kh + 128*72;     // total 73,728 B

  const int t  = threadIdx.x;
  const int qt = blockIdx.x, kt = blockIdx.y;
  const int bh = bh0 + blockIdx.z;
  const size_t qbase = ((size_t)bh*NQ + qt*128) * 64;
  const size_t kbase = ((size_t)bh*NK + kt*128) * 64;

  #pragma unroll
  for (int i = 0; i < 4; ++i) {
    int c   = t + i*256;        // chunk 0..1023 (16 B each)
    int row = c >> 3, off = (c & 7) * 8;
    *(u16x8*)(qh + row*72 + off) = *(const u16x8*)(Qhi + qbase + row*64 + off);
    *(u16x8*)(ql + row*72 + off) = *(const u16x8*)(Qlo + qbase + row*64 + off);
    *(u16x8*)(kh + row*72 + off) = *(const u16x8*)(Khi + kbase + row*64 + off);
    *(u16x8*)(kl + row*72 + off) = *(const u16x8*)(Klo + kbase + row*64 + off);
  }
  __syncthreads();

  const int w = t >> 6, l = t & 63;
  const int quad = l >> 4, lr = l & 15;

  frag_ab aH[2][2], aL[2][2];
  #pragma unroll
  for (int qs = 0; qs < 2; ++qs) {
    int row = w*32 + qs*16 + lr;
    #pragma unroll
    for (int s = 0; s < 2; ++s) {
      aH[qs][s] = *(const frag_ab*)(qh + row*72 + s*32 + quad*8);
      aL[qs][s] = *(const frag_ab*)(ql + row*72 + s*32 + quad*8);
    }
  }

  for (int ks = 0; ks < 8; ++ks) {
    frag_ab bH[2], bL[2];
    int krow = ks*16 + lr;
    #pragma unroll
    for (int s = 0; s < 2; ++s) {
      bH[s] = *(const frag_ab*)(kh + krow*72 + s*32 + quad*8);
      bL[s] = *(const frag_ab*)(kl + krow*72 + s*32 + quad*8);
    }
    #pragma unroll
    for (int qs = 0; qs < 2; ++qs) {
      frag_cd c = {0.f, 0.f, 0.f, 0.f};
      #pragma unroll
      for (int s = 0; s < 2; ++s) {
        c = __builtin_amdgcn_mfma_f32_16x16x32_bf16(aH[qs][s], bH[s], c, 0, 0, 0);
        c = __builtin_amdgcn_mfma_f32_16x16x32_bf16(aH[qs][s], bL[s], c, 0, 0, 0);
        c = __builtin_amdgcn_mfma_f32_16x16x32_bf16(aL[qs][s], bH[s], c, 0, 0, 0);
      }
      int qrow = qt*128 + w*32 + qs*16 + quad*4;   // + i
      int kcol = kt*128 + ks*16 + lr;
      size_t base = ((size_t)blockIdx.z * NQ + qrow) * NK + kcol;
      #pragma unroll
      for (int i = 0; i < 4; ++i)
        S[base + (size_t)i*NK] = c[i] * 0.125f;
    }
  }
}

// ---------------------------------------------------------------------------
// Select: per wave one query row of the chunk. Exact fp32-bits kth via binary
// search, margin collect (skth - 1e-3) -> cand/cnt (global row indexing).
// ---------------------------------------------------------------------------
__global__ __launch_bounds__(256) void select_rows(
    const float* __restrict__ S, unsigned short* __restrict__ cand,
    int* __restrict__ cnt, const int* __restrict__ topkp, int row0)
{
  const int t = threadIdx.x;
  const int w = t >> 6, l = t & 63;
  const int rl = blockIdx.x * 4 + w;
  const size_t row = (size_t)row0 + rl;
  const float* Sr = S + (size_t)rl * NK;
  const unsigned long long lmask = (1ull << l) - 1ull;

  int kEff = *topkp;
  if (kEff > CAND_MAX) kEff = CAND_MAX;
  if (kEff < 1) kEff = 1;

  unsigned uv[32];
  #pragma unroll
  for (int c = 0; c < 32; ++c) {
    unsigned bb = __float_as_uint(Sr[c*64 + l]);
    uv[c] = (bb & 0x80000000u) ? ~bb : (bb | 0x80000000u);
  }
  unsigned lo_ = 0u, hi_ = 0xFFFFFFFFu;
  while (lo_ < hi_) {
    unsigned mid = (unsigned)(((unsigned long long)lo_ + (unsigned long long)hi_ + 1ull) >> 1);
    int c_ = 0;
    #pragma unroll
    for (int c = 0; c < 32; ++c) c_ += (uv[c] >= mid) ? 1 : 0;
    #pragma unroll
    for (int off = 32; off > 0; off >>= 1) c_ += __shfl_xor(c_, off);
    if (c_ >= kEff) lo_ = mid; else hi_ = mid - 1;
  }
  const unsigned uth = lo_;
  float skth = __uint_as_float((uth & 0x80000000u) ? (uth & 0x7FFFFFFFu) : ~uth);
  float smarg = skth - 1e-3f;   // margin >> bf16x3 score err
  unsigned b2 = __float_as_uint(smarg);
  unsigned um = (b2 & 0x80000000u) ? ~b2 : (b2 | 0x80000000u);

  int base = 0;
  for (int c = 0; c < 32; ++c) {
    bool pred = (uv[c] >= um);
    unsigned long long msk = __ballot(pred);
    if (pred) {
      int pos = base + __popcll(msk & lmask);
      if (pos < CAND_MAX) cand[row*CAND_MAX + pos] = (unsigned short)(c*64 + l);
    }
    base += __popcll(msk);
  }
  if (l == 0) cnt[row] = (base < CAND_MAX) ? base : CAND_MAX;
}

// ---------------------------------------------------------------------------
// Phase B: f64 re-score, exact kth; if 64th-65th gap < 2*DELTA use a linear
// membership ramp (pair memberships sum to 1) instead of a hard cut; softmax
// + PV (fp32 V), write inner.  (proven in round 4)
// ---------------------------------------------------------------------------
__global__ __launch_bounds__(256) void attn_phase_b(
    const double* __restrict__ Q64, const double* __restrict__ K64,
    const float* __restrict__ V32, const unsigned short* __restrict__ cand,
    const int* __restrict__ cnt, float* __restrict__ inner,
    const int* __restrict__ topkp)
{
  const int t = threadIdx.x;
  const int w = t >> 6, l = t & 63;
  const size_t row = (size_t)blockIdx.x * 4 + w;
  const int bh = (int)(row >> 11);
  const int q  = (int)(row & (NQ - 1));
  const unsigned long long lmask = (1ull << l) - 1ull;

  int kEff = *topkp;
  if (kEff > CAND_MAX) kEff = CAND_MAX;
  if (kEff < 1) kEff = 1;
  int m = cnt[row];
  if (kEff > m) kEff = m;

  const double qv = Q64[row*64 + l];
  const double* Kb = K64 + (size_t)bh * NK * 64;
  const float*  Vb = V32 + (size_t)bh * NK * 64;

  int ck[2];
  ck[0] = cand[row*CAND_MAX + l];
  ck[1] = cand[row*CAND_MAX + 64 + l];
  double cs[2] = {-INFINITY, -INFINITY};
  unsigned long long cu[2] = {0ull, 0ull};

  for (int j = 0; j < m; ++j) {
    int c = j >> 6;
    int key = __shfl(ck[c], j & 63);
    double p = qv * Kb[(size_t)key*64 + l];
    #pragma unroll
    for (int off = 1; off < 64; off <<= 1) p += __shfl_xor(p, off);
    double s = p * 0.125;
    if (l == (j & 63)) {
      unsigned long long b = (unsigned long long)__double_as_longlong(s);
      cs[c] = s;
      cu[c] = (b >> 63) ? ~b : (b | 0x8000000000000000ull);
    }
  }

  unsigned long long T = 0ull;
  for (int bit = 63; bit >= 0; --bit) {
    unsigned long long cT = T | (1ull << bit);
    int tot = __popcll(__ballot(cu[0] >= cT)) + __popcll(__ballot(cu[1] >= cT));
    if (tot >= kEff) T = cT;
  }
  double s_kth;
  { unsigned long long bb = (T >> 63) ? (T & 0x7FFFFFFFFFFFFFFFull) : ~T;
    s_kth = __longlong_as_double((long long)bb); }

  double nx = -INFINITY;
  #pragma unroll
  for (int c = 0; c < 2; ++c) { double v = (cu[c] < T) ? cs[c] : -INFINITY; nx = fmax(nx, v); }
  #pragma unroll
  for (int off = 32; off > 0; off >>= 1) nx = fmax(nx, __shfl_xor(nx, off));

  double smax = fmax(cs[0], cs[1]);
  #pragma unroll
  for (int off = 32; off > 0; off >>= 1) smax = fmax(smax, __shfl_xor(smax, off));

  const double DELTA = 5e-6;
  float wgt[2];
  if (!(s_kth - nx < 2.0*DELTA)) {
    int cgt = __popcll(__ballot(cu[0] > T)) + __popcll(__ballot(cu[1] > T));
    int nEq = kEff - cgt;
    int eqBase = 0;
    #pragma unroll
    for (int c = 0; c < 2; ++c) {
      bool eq = (cu[c] == T);
      unsigned long long eqm = __ballot(eq);
      int er = __popcll(eqm & lmask);
      bool sel = (cu[c] > T) || (eq && (eqBase + er) < nEq);
      eqBase += __popcll(eqm);
      wgt[c] = sel ? (float)exp(cs[c] - smax) : 0.f;
    }
  } else {
    double cmid = 0.5 * (s_kth + nx);
    #pragma unroll
    for (int c = 0; c < 2; ++c) {
      double mu = 0.5 + (cs[c] - cmid) / (2.0*DELTA);
      mu = fmin(1.0, fmax(0.0, mu));
      wgt[c] = (float)(mu * exp(cs[c] - smax));
    }
  }

  float acc = 0.f, wsum = 0.f;
  for (int j = 0; j < m; ++j) {
    int c = j >> 6;
    float wj = __shfl(wgt[c], j & 63);
    if (wj != 0.f) {
      int key = __shfl(ck[c], j & 63);
      wsum += wj;
      acc = fmaf(wj, Vb[(size_t)key*64 + l], acc);
    }
  }
  int b = bh >> 3, h = bh & 7;
  inner[((size_t)b*NQ + q)*INNER + h*DHEAD + l] = acc / wsum;
}

// ---------------------------------------------------------------------------
extern "C" void kernel_launch(void* const* d_in, const int* in_sizes, int n_in,
                              void* d_out, int out_size, void* d_ws, size_t ws_size,
                              hipStream_t stream)
{
  const float* x    = (const float*)d_in[0];
  const float* ctx  = (const float*)d_in[1];
  const float* Wq   = (const float*)d_in[2];
  const float* Wkv  = (const float*)d_in[3];
  const float* Wout = (const float*)d_in[4];
  const float* bout = (const float*)d_in[5];
  const int*   topk = (const int*)d_in[6];
  float* out = (float*)d_out;

  const size_t SZ = (size_t)BATCH * NHEADS * NQ * DHEAD;  // 4,194,304

  // ---- ws layout (fixed 112.5 MB) + adaptive score slab + aliasing ----
  size_t off = 0;
  char* base = (char*)d_ws;
  auto take = [&](size_t bytes) { char* r = base + off; off += (bytes + 255) & ~(size_t)255; return r; };
  double* Q64 = (double*)take(SZ * sizeof(double));                        // 32 MB
  double* K64 = (double*)take(SZ * sizeof(double));                        // 32 MB
  unsigned short* cand = (unsigned short*)take((size_t)NROWS * CAND_MAX * 2); // 16 MB
  int* cnt = (int*)take((size_t)NROWS * sizeof(int));                      // 256 KB
  unsigned short* Qhi = (unsigned short*)take(SZ * 2);                     // 8 MB
  unsigned short* Qlo = (unsigned short*)take(SZ * 2);                     // 8 MB
  unsigned short* Khi = (unsigned short*)take(SZ * 2);                     // 8 MB
  unsigned short* Klo = (unsigned short*)take(SZ * 2);                     // 8 MB
  float* S = (float*)(base + off);          // remainder: score slab
  // Aliases (live only after score/select complete):
  float* V32   = (float*)Qhi;               // 16 MB over Qhi+Qlo
  float* inner = (float*)Khi;               // 16 MB over Khi+Klo

  const size_t per_bh = (size_t)NQ * NK * sizeof(float);  // 16 MB
  size_t avail = (ws_size > off) ? (ws_size - off) : 0;
  int bhchunk = (int)(avail / per_bh);
  if (bhchunk < 1)  bhchunk = 1;     // (requires ws_size >= ~128.5 MB)
  if (bhchunk > 32) bhchunk = 32;

  const int M = BATCH * NQ;  // 8192
  const int SCORE_LDS = 4 * 128 * 72 * (int)sizeof(unsigned short); // 73,728 B
  hipFuncSetAttribute(reinterpret_cast<const void*>(score_mfma),
                      hipFuncAttributeMaxDynamicSharedMemorySize, SCORE_LDS);

  gemm_f64_proj<<<dim3(INNER/64, M/64), 256, 0, stream>>>(x,   Wq,  INNER,   0, Q64, Qhi, Qlo);
  gemm_f64_proj<<<dim3(INNER/64, M/64), 256, 0, stream>>>(ctx, Wkv, 2*INNER, 0, K64, Khi, Klo);

  for (int c0 = 0; c0 < BATCH*NHEADS; c0 += bhchunk) {
    int cc = BATCH*NHEADS - c0; if (cc > bhchunk) cc = bhchunk;
    score_mfma<<<dim3(NQ/128, NK/128, cc), 256, SCORE_LDS, stream>>>(
        Qhi, Qlo, Khi, Klo, S, c0);
    select_rows<<<dim3(cc*NQ/4), 256, 0, stream>>>(S, cand, cnt, topk, c0*NQ);
  }

  // V32 overwrites Qhi/Qlo (dead), inner overwrites Khi/Klo (dead).
  gemm_f32<2><<<dim3(INNER/64, M/64), 256, 0, stream>>>(ctx, Wkv, 2*INNER, INNER, nullptr, V32, M, INNER, DQ);
  attn_phase_b<<<dim3(NROWS/4), 256, 0, stream>>>(Q64, K64, V32, cand, cnt, inner, topk);
  gemm_f32<0><<<dim3(DQ/64, M/64), 256, 0, stream>>>(inner, Wout, DQ, 0, bout, out, M, DQ, INNER);
}

// Round 7
// 1993.227 us; speedup vs baseline: 1.7241x; 1.1478x over previous
//
#include <hip/hip_runtime.h>
#include <math.h>

#define BATCH 4
#define NQ 2048
#define NK 2048
#define DQ 1024
#define NHEADS 8
#define DHEAD 64
#define INNER (NHEADS*DHEAD)     // 512
#define NROWS (BATCH*NHEADS*NQ)  // 65536
#define CAND_MAX 128

using frag_ab = __attribute__((ext_vector_type(8))) short;   // 8 bf16
using frag_cd = __attribute__((ext_vector_type(4))) float;   // 4 fp32
using u16x8   = __attribute__((ext_vector_type(8))) unsigned short;

static __device__ __forceinline__ unsigned short f32_to_bf16_rne(float f) {
  unsigned u = __float_as_uint(f);
  u += 0x7FFFu + ((u >> 16) & 1u);
  return (unsigned short)(u >> 16);
}

// ---------------------------------------------------------------------------
// f64-accumulate projection GEMM (fp32 in): C64[bh][n][d] scatter.
// Epilogue also emits bf16 hi/lo split (for MFMA scoring).
// ---------------------------------------------------------------------------
__global__ __launch_bounds__(256) void gemm_f64_proj(
    const float* __restrict__ A, const float* __restrict__ Bm,
    int ldb, int bcoloff, double* __restrict__ C64,
    unsigned short* __restrict__ Hi, unsigned short* __restrict__ Lo)
{
  __shared__ double As[16*66];  // [k][m]
  __shared__ double Bs[16*66];  // [k][n]
  const int t  = threadIdx.x;
  const int tx = t & 15, ty = t >> 4;
  const int n0 = blockIdx.x * 64, m0 = blockIdx.y * 64;
  double acc[4][4] = {};

  for (int kt = 0; kt < DQ; kt += 16) {
    int m  = t >> 2;
    int c4 = (t & 3) * 4;
    const float4 av = *(const float4*)(A + (size_t)(m0 + m) * DQ + kt + c4);
    int k  = t >> 4;
    int n4 = (t & 15) * 4;
    const float4 bv = *(const float4*)(Bm + (size_t)(kt + k) * ldb + bcoloff + n0 + n4);
    As[(c4+0)*66 + m] = (double)av.x;
    As[(c4+1)*66 + m] = (double)av.y;
    As[(c4+2)*66 + m] = (double)av.z;
    As[(c4+3)*66 + m] = (double)av.w;
    Bs[k*66 + n4+0] = (double)bv.x;
    Bs[k*66 + n4+1] = (double)bv.y;
    Bs[k*66 + n4+2] = (double)bv.z;
    Bs[k*66 + n4+3] = (double)bv.w;
    __syncthreads();
    #pragma unroll
    for (int kk = 0; kk < 16; ++kk) {
      double av_[4], bv_[4];
      #pragma unroll
      for (int i = 0; i < 4; ++i) { av_[i] = As[kk*66 + ty*4+i]; bv_[i] = Bs[kk*66 + tx*4+i]; }
      #pragma unroll
      for (int i = 0; i < 4; ++i)
        #pragma unroll
        for (int j = 0; j < 4; ++j)
          acc[i][j] = fma(av_[i], bv_[j], acc[i][j]);
    }
    __syncthreads();
  }

  #pragma unroll
  for (int i = 0; i < 4; ++i) {
    int r = m0 + ty*4 + i;
    int b = r >> 11, n = r & (NQ - 1);
    #pragma unroll
    for (int j = 0; j < 4; ++j) {
      int cc = n0 + tx*4 + j;
      int h = cc >> 6, d = cc & 63;
      size_t idx = (((size_t)(b*NHEADS + h))*NQ + n)*64 + d;
      C64[idx] = acc[i][j];
      float v = (float)acc[i][j];
      unsigned short hb = f32_to_bf16_rne(v);
      float hf = __uint_as_float((unsigned)hb << 16);
      unsigned short lb = f32_to_bf16_rne(v - hf);
      Hi[idx] = hb;
      Lo[idx] = lb;
    }
  }
}

// ---------------------------------------------------------------------------
// fp32 GEMM.  MODE 0: +bias, row-major C0[M][N].  MODE 2: scatter V[bh][n][d].
// ---------------------------------------------------------------------------
template<int MODE>
__global__ __launch_bounds__(256) void gemm_f32(
    const float* __restrict__ A, const float* __restrict__ Bm,
    int ldb, int bcoloff, const float* __restrict__ bias,
    float* __restrict__ C0, int M, int N, int K)
{
  __shared__ float As[16*68];
  __shared__ float Bs[16*68];
  const int t  = threadIdx.x;
  const int tx = t & 15, ty = t >> 4;
  const int n0 = blockIdx.x * 64, m0 = blockIdx.y * 64;
  float acc[4][4] = {};

  for (int kt = 0; kt < K; kt += 16) {
    int m  = t >> 2;
    int c4 = (t & 3) * 4;
    const float4 av = *(const float4*)(A + (size_t)(m0 + m) * K + kt + c4);
    As[(c4+0)*68 + m] = av.x;
    As[(c4+1)*68 + m] = av.y;
    As[(c4+2)*68 + m] = av.z;
    As[(c4+3)*68 + m] = av.w;
    int k  = t >> 4;
    int n4 = (t & 15) * 4;
    const float4 bv = *(const float4*)(Bm + (size_t)(kt + k) * ldb + bcoloff + n0 + n4);
    *(float4*)(Bs + k*68 + n4) = bv;
    __syncthreads();
    #pragma unroll
    for (int kk = 0; kk < 16; ++kk) {
      float4 a4 = *(const float4*)(As + kk*68 + ty*4);
      float4 b4 = *(const float4*)(Bs + kk*68 + tx*4);
      float av_[4] = {a4.x, a4.y, a4.z, a4.w};
      float bv_[4] = {b4.x, b4.y, b4.z, b4.w};
      #pragma unroll
      for (int i = 0; i < 4; ++i)
        #pragma unroll
        for (int j = 0; j < 4; ++j)
          acc[i][j] = fmaf(av_[i], bv_[j], acc[i][j]);
    }
    __syncthreads();
  }

  #pragma unroll
  for (int i = 0; i < 4; ++i) {
    int r = m0 + ty*4 + i;
    int b = r >> 11, n = r & (NQ - 1);
    #pragma unroll
    for (int j = 0; j < 4; ++j) {
      int cc = n0 + tx*4 + j;
      if (MODE == 0) {
        C0[(size_t)r * N + cc] = acc[i][j] + bias[cc];
      } else {
        int h = cc >> 6, d = cc & 63;
        C0[(((size_t)(b*NHEADS + h))*NK + n)*64 + d] = acc[i][j];
      }
    }
  }
}

// ---------------------------------------------------------------------------
// Score GEMM via bf16x3 MFMA: S[bh_local][q][k] = 0.125 * (q . k), fp32.
// ---------------------------------------------------------------------------
__global__ __launch_bounds__(256) void score_mfma(
    const unsigned short* __restrict__ Qhi, const unsigned short* __restrict__ Qlo,
    const unsigned short* __restrict__ Khi, const unsigned short* __restrict__ Klo,
    float* __restrict__ S, int bh0)
{
  extern __shared__ unsigned short sm[];
  unsigned short* qh = sm;              // 128*72
  unsigned short* ql = qh + 128*72;
  unsigned short* kh = ql + 128*72;
  unsigned short* kl = kh + 128*72;     // total 73,728 B

  const int t  = threadIdx.x;
  const int qt = blockIdx.x, kt = blockIdx.y;
  const int bh = bh0 + blockIdx.z;
  const size_t qbase = ((size_t)bh*NQ + qt*128) * 64;
  const size_t kbase = ((size_t)bh*NK + kt*128) * 64;

  #pragma unroll
  for (int i = 0; i < 4; ++i) {
    int c   = t + i*256;        // chunk 0..1023 (16 B each)
    int row = c >> 3, off = (c & 7) * 8;
    *(u16x8*)(qh + row*72 + off) = *(const u16x8*)(Qhi + qbase + row*64 + off);
    *(u16x8*)(ql + row*72 + off) = *(const u16x8*)(Qlo + qbase + row*64 + off);
    *(u16x8*)(kh + row*72 + off) = *(const u16x8*)(Khi + kbase + row*64 + off);
    *(u16x8*)(kl + row*72 + off) = *(const u16x8*)(Klo + kbase + row*64 + off);
  }
  __syncthreads();

  const int w = t >> 6, l = t & 63;
  const int quad = l >> 4, lr = l & 15;

  frag_ab aH[2][2], aL[2][2];
  #pragma unroll
  for (int qs = 0; qs < 2; ++qs) {
    int row = w*32 + qs*16 + lr;
    #pragma unroll
    for (int s = 0; s < 2; ++s) {
      aH[qs][s] = *(const frag_ab*)(qh + row*72 + s*32 + quad*8);
      aL[qs][s] = *(const frag_ab*)(ql + row*72 + s*32 + quad*8);
    }
  }

  for (int ks = 0; ks < 8; ++ks) {
    frag_ab bH[2], bL[2];
    int krow = ks*16 + lr;
    #pragma unroll
    for (int s = 0; s < 2; ++s) {
      bH[s] = *(const frag_ab*)(kh + krow*72 + s*32 + quad*8);
      bL[s] = *(const frag_ab*)(kl + krow*72 + s*32 + quad*8);
    }
    #pragma unroll
    for (int qs = 0; qs < 2; ++qs) {
      frag_cd c = {0.f, 0.f, 0.f, 0.f};
      #pragma unroll
      for (int s = 0; s < 2; ++s) {
        c = __builtin_amdgcn_mfma_f32_16x16x32_bf16(aH[qs][s], bH[s], c, 0, 0, 0);
        c = __builtin_amdgcn_mfma_f32_16x16x32_bf16(aH[qs][s], bL[s], c, 0, 0, 0);
        c = __builtin_amdgcn_mfma_f32_16x16x32_bf16(aL[qs][s], bH[s], c, 0, 0, 0);
      }
      int qrow = qt*128 + w*32 + qs*16 + quad*4;   // + i
      int kcol = kt*128 + ks*16 + lr;
      size_t base = ((size_t)blockIdx.z * NQ + qrow) * NK + kcol;
      #pragma unroll
      for (int i = 0; i < 4; ++i)
        S[base + (size_t)i*NK] = c[i] * 0.125f;
    }
  }
}

// ---------------------------------------------------------------------------
// Select: per wave one query row of the chunk. Exact fp32-bits kth via binary
// search, margin collect (skth - 1e-3) -> cand/cnt (global row indexing).
// ---------------------------------------------------------------------------
__global__ __launch_bounds__(256) void select_rows(
    const float* __restrict__ S, unsigned short* __restrict__ cand,
    int* __restrict__ cnt, const int* __restrict__ topkp, int row0)
{
  const int t = threadIdx.x;
  const int w = t >> 6, l = t & 63;
  const int rl = blockIdx.x * 4 + w;
  const size_t row = (size_t)row0 + rl;
  const float* Sr = S + (size_t)rl * NK;
  const unsigned long long lmask = (1ull << l) - 1ull;

  int kEff = *topkp;
  if (kEff > CAND_MAX) kEff = CAND_MAX;
  if (kEff < 1) kEff = 1;

  unsigned uv[32];
  #pragma unroll
  for (int c = 0; c < 32; ++c) {
    unsigned bb = __float_as_uint(Sr[c*64 + l]);
    uv[c] = (bb & 0x80000000u) ? ~bb : (bb | 0x80000000u);
  }
  unsigned lo_ = 0u, hi_ = 0xFFFFFFFFu;
  while (lo_ < hi_) {
    unsigned mid = (unsigned)(((unsigned long long)lo_ + (unsigned long long)hi_ + 1ull) >> 1);
    int c_ = 0;
    #pragma unroll
    for (int c = 0; c < 32; ++c) c_ += (uv[c] >= mid) ? 1 : 0;
    #pragma unroll
    for (int off = 32; off > 0; off >>= 1) c_ += __shfl_xor(c_, off);
    if (c_ >= kEff) lo_ = mid; else hi_ = mid - 1;
  }
  const unsigned uth = lo_;
  float skth = __uint_as_float((uth & 0x80000000u) ? (uth & 0x7FFFFFFFu) : ~uth);
  float smarg = skth - 1e-3f;   // margin >> bf16x3 score err
  unsigned b2 = __float_as_uint(smarg);
  unsigned um = (b2 & 0x80000000u) ? ~b2 : (b2 | 0x80000000u);

  int base = 0;
  for (int c = 0; c < 32; ++c) {
    bool pred = (uv[c] >= um);
    unsigned long long msk = __ballot(pred);
    if (pred) {
      int pos = base + __popcll(msk & lmask);
      if (pos < CAND_MAX) cand[row*CAND_MAX + pos] = (unsigned short)(c*64 + l);
    }
    base += __popcll(msk);
  }
  if (l == 0) cnt[row] = (base < CAND_MAX) ? base : CAND_MAX;
}

// ---------------------------------------------------------------------------
// Phase B: lane-per-candidate f64 re-score (double2 gathers, readlane q
// broadcast), exact u64 kth, delta-blend boundary, softmax + PV, write inner.
// ---------------------------------------------------------------------------
__global__ __launch_bounds__(256) void attn_phase_b(
    const double* __restrict__ Q64, const double* __restrict__ K64,
    const float* __restrict__ V32, const unsigned short* __restrict__ cand,
    const int* __restrict__ cnt, float* __restrict__ inner,
    const int* __restrict__ topkp)
{
  const int t = threadIdx.x;
  const int w = t >> 6, l = t & 63;
  const size_t row = (size_t)blockIdx.x * 4 + w;
  const int bh = (int)(row >> 11);
  const int q  = (int)(row & (NQ - 1));
  const unsigned long long lmask = (1ull << l) - 1ull;

  int kEff = *topkp;
  if (kEff > CAND_MAX) kEff = CAND_MAX;
  if (kEff < 1) kEff = 1;
  int m = cnt[row];
  if (kEff > m) kEff = m;

  const double qv = Q64[row*64 + l];
  const double* Kb = K64 + (size_t)bh * NK * 64;
  const float*  Vb = V32 + (size_t)bh * NK * 64;

  int ck[2];
  ck[0] = cand[row*CAND_MAX + l];
  ck[1] = cand[row*CAND_MAX + 64 + l];
  double cs[2] = {-INFINITY, -INFINITY};
  unsigned long long cu[2] = {0ull, 0ull};

  // batch 0: lanes 0..m-1 own candidates 0..m-1 (parallel gather-dot)
  {
    const bool valid = (l < m);
    const double* kp = Kb + (size_t)(valid ? ck[0] : 0) * 64;
    double sA = 0.0, sB = 0.0;
    #pragma unroll 8
    for (int d = 0; d < 64; d += 2) {
      double qa = __shfl(qv, d);
      double qb = __shfl(qv, d + 1);
      double2 kv = *(const double2*)(kp + d);
      sA = fma(kv.x, qa, sA);
      sB = fma(kv.y, qb, sB);
    }
    if (valid) {
      double sc = (sA + sB) * 0.125;
      unsigned long long b = (unsigned long long)__double_as_longlong(sc);
      cs[0] = sc;
      cu[0] = (b >> 63) ? ~b : (b | 0x8000000000000000ull);
    }
  }
  // batch 1 (rare, m>64): wave-uniform branch
  if (m > 64) {
    const bool valid = (64 + l < m);
    const double* kp = Kb + (size_t)(valid ? ck[1] : 0) * 64;
    double sA = 0.0, sB = 0.0;
    #pragma unroll 8
    for (int d = 0; d < 64; d += 2) {
      double qa = __shfl(qv, d);
      double qb = __shfl(qv, d + 1);
      double2 kv = *(const double2*)(kp + d);
      sA = fma(kv.x, qa, sA);
      sB = fma(kv.y, qb, sB);
    }
    if (valid) {
      double sc = (sA + sB) * 0.125;
      unsigned long long b = (unsigned long long)__double_as_longlong(sc);
      cs[1] = sc;
      cu[1] = (b >> 63) ? ~b : (b | 0x8000000000000000ull);
    }
  }

  // exact kth largest u64
  unsigned long long T = 0ull;
  if (m > 64) {
    for (int bit = 63; bit >= 0; --bit) {
      unsigned long long cT = T | (1ull << bit);
      int tot = __popcll(__ballot(cu[0] >= cT)) + __popcll(__ballot(cu[1] >= cT));
      if (tot >= kEff) T = cT;
    }
  } else {
    for (int bit = 63; bit >= 0; --bit) {
      unsigned long long cT = T | (1ull << bit);
      int tot = __popcll(__ballot(cu[0] >= cT));
      if (tot >= kEff) T = cT;
    }
  }
  double s_kth;
  { unsigned long long bb = (T >> 63) ? (T & 0x7FFFFFFFFFFFFFFFull) : ~T;
    s_kth = __longlong_as_double((long long)bb); }

  double nx = -INFINITY;
  #pragma unroll
  for (int c = 0; c < 2; ++c) { double v = (cu[c] < T) ? cs[c] : -INFINITY; nx = fmax(nx, v); }
  #pragma unroll
  for (int off = 32; off > 0; off >>= 1) nx = fmax(nx, __shfl_xor(nx, off));

  double smax = fmax(cs[0], cs[1]);
  #pragma unroll
  for (int off = 32; off > 0; off >>= 1) smax = fmax(smax, __shfl_xor(smax, off));

  const double DELTA = 5e-6;
  float wgt[2];
  if (!(s_kth - nx < 2.0*DELTA)) {
    int cgt = __popcll(__ballot(cu[0] > T)) + __popcll(__ballot(cu[1] > T));
    int nEq = kEff - cgt;
    int eqBase = 0;
    #pragma unroll
    for (int c = 0; c < 2; ++c) {
      bool eq = (cu[c] == T);
      unsigned long long eqm = __ballot(eq);
      int er = __popcll(eqm & lmask);
      bool sel = (cu[c] > T) || (eq && (eqBase + er) < nEq);
      eqBase += __popcll(eqm);
      wgt[c] = sel ? (float)exp(cs[c] - smax) : 0.f;
    }
  } else {
    double cmid = 0.5 * (s_kth + nx);
    #pragma unroll
    for (int c = 0; c < 2; ++c) {
      double mu = 0.5 + (cs[c] - cmid) / (2.0*DELTA);
      mu = fmin(1.0, fmax(0.0, mu));
      wgt[c] = (float)(mu * exp(cs[c] - smax));
    }
  }

  float acc = 0.f, wsum = 0.f;
  for (int j = 0; j < m; ++j) {
    int c = j >> 6;
    float wj = __shfl(wgt[c], j & 63);
    if (wj != 0.f) {
      int key = __shfl(ck[c], j & 63);
      wsum += wj;
      acc = fmaf(wj, Vb[(size_t)key*64 + l], acc);
    }
  }
  int b = bh >> 3, h = bh & 7;
  inner[((size_t)b*NQ + q)*INNER + h*DHEAD + l] = acc / wsum;
}

// ---------------------------------------------------------------------------
extern "C" void kernel_launch(void* const* d_in, const int* in_sizes, int n_in,
                              void* d_out, int out_size, void* d_ws, size_t ws_size,
                              hipStream_t stream)
{
  const float* x    = (const float*)d_in[0];
  const float* ctx  = (const float*)d_in[1];
  const float* Wq   = (const float*)d_in[2];
  const float* Wkv  = (const float*)d_in[3];
  const float* Wout = (const float*)d_in[4];
  const float* bout = (const float*)d_in[5];
  const int*   topk = (const int*)d_in[6];
  float* out = (float*)d_out;

  const size_t SZ = (size_t)BATCH * NHEADS * NQ * DHEAD;  // 4,194,304

  // ---- ws layout (fixed 112.5 MB) + adaptive score slab + aliasing ----
  size_t off = 0;
  char* base = (char*)d_ws;
  auto take = [&](size_t bytes) { char* r = base + off; off += (bytes + 255) & ~(size_t)255; return r; };
  double* Q64 = (double*)take(SZ * sizeof(double));                        // 32 MB
  double* K64 = (double*)take(SZ * sizeof(double));                        // 32 MB
  unsigned short* cand = (unsigned short*)take((size_t)NROWS * CAND_MAX * 2); // 16 MB
  int* cnt = (int*)take((size_t)NROWS * sizeof(int));                      // 256 KB
  unsigned short* Qhi = (unsigned short*)take(SZ * 2);                     // 8 MB
  unsigned short* Qlo = (unsigned short*)take(SZ * 2);                     // 8 MB
  unsigned short* Khi = (unsigned short*)take(SZ * 2);                     // 8 MB
  unsigned short* Klo = (unsigned short*)take(SZ * 2);                     // 8 MB
  float* S = (float*)(base + off);          // remainder: score slab
  // Aliases (live only after score/select complete):
  float* V32   = (float*)Qhi;               // 16 MB over Qhi+Qlo
  float* inner = (float*)Khi;               // 16 MB over Khi+Klo

  const size_t per_bh = (size_t)NQ * NK * sizeof(float);  // 16 MB
  size_t avail = (ws_size > off) ? (ws_size - off) : 0;
  int bhchunk = (int)(avail / per_bh);
  if (bhchunk < 1)  bhchunk = 1;     // (requires ws_size >= ~128.5 MB)
  if (bhchunk > 32) bhchunk = 32;

  const int M = BATCH * NQ;  // 8192
  const int SCORE_LDS = 4 * 128 * 72 * (int)sizeof(unsigned short); // 73,728 B
  hipFuncSetAttribute(reinterpret_cast<const void*>(score_mfma),
                      hipFuncAttributeMaxDynamicSharedMemorySize, SCORE_LDS);

  gemm_f64_proj<<<dim3(INNER/64, M/64), 256, 0, stream>>>(x,   Wq,  INNER,   0, Q64, Qhi, Qlo);
  gemm_f64_proj<<<dim3(INNER/64, M/64), 256, 0, stream>>>(ctx, Wkv, 2*INNER, 0, K64, Khi, Klo);

  for (int c0 = 0; c0 < BATCH*NHEADS; c0 += bhchunk) {
    int cc = BATCH*NHEADS - c0; if (cc > bhchunk) cc = bhchunk;
    score_mfma<<<dim3(NQ/128, NK/128, cc), 256, SCORE_LDS, stream>>>(
        Qhi, Qlo, Khi, Klo, S, c0);
    select_rows<<<dim3(cc*NQ/4), 256, 0, stream>>>(S, cand, cnt, topk, c0*NQ);
  }

  // V32 overwrites Qhi/Qlo (dead), inner overwrites Khi/Klo (dead).
  gemm_f32<2><<<dim3(INNER/64, M/64), 256, 0, stream>>>(ctx, Wkv, 2*INNER, INNER, nullptr, V32, M, INNER, DQ);
  attn_phase_b<<<dim3(NROWS/4), 256, 0, stream>>>(Q64, K64, V32, cand, cnt, inner, topk);
  gemm_f32<0><<<dim3(DQ/64, M/64), 256, 0, stream>>>(inner, Wout, DQ, 0, bout, out, M, DQ, INNER);
}

// Round 8
// 1742.492 us; speedup vs baseline: 1.9722x; 1.1439x over previous
//
#include <hip/hip_runtime.h>
#include <math.h>

#define BATCH 4
#define NQ 2048
#define NK 2048
#define DQ 1024
#define NHEADS 8
#define DHEAD 64
#define INNER (NHEADS*DHEAD)     // 512
#define NROWS (BATCH*NHEADS*NQ)  // 65536
#define CAND_MAX 128

using frag_ab = __attribute__((ext_vector_type(8))) short;   // 8 bf16
using frag_cd = __attribute__((ext_vector_type(4))) float;   // 4 fp32
using u16x8   = __attribute__((ext_vector_type(8))) unsigned short;

static __device__ __forceinline__ unsigned short f32_to_bf16_rne(float f) {
  unsigned u = __float_as_uint(f);
  u += 0x7FFFu + ((u >> 16) & 1u);
  return (unsigned short)(u >> 16);
}

// ---------------------------------------------------------------------------
// f64-accumulate projection GEMM (fp32 in): C64[bh][n][d] scatter.
// Epilogue also emits bf16 hi/lo split (for MFMA scoring).
// ---------------------------------------------------------------------------
__global__ __launch_bounds__(256) void gemm_f64_proj(
    const float* __restrict__ A, const float* __restrict__ Bm,
    int ldb, int bcoloff, double* __restrict__ C64,
    unsigned short* __restrict__ Hi, unsigned short* __restrict__ Lo)
{
  __shared__ double As[16*66];  // [k][m]
  __shared__ double Bs[16*66];  // [k][n]
  const int t  = threadIdx.x;
  const int tx = t & 15, ty = t >> 4;
  const int n0 = blockIdx.x * 64, m0 = blockIdx.y * 64;
  double acc[4][4] = {};

  for (int kt = 0; kt < DQ; kt += 16) {
    int m  = t >> 2;
    int c4 = (t & 3) * 4;
    const float4 av = *(const float4*)(A + (size_t)(m0 + m) * DQ + kt + c4);
    int k  = t >> 4;
    int n4 = (t & 15) * 4;
    const float4 bv = *(const float4*)(Bm + (size_t)(kt + k) * ldb + bcoloff + n0 + n4);
    As[(c4+0)*66 + m] = (double)av.x;
    As[(c4+1)*66 + m] = (double)av.y;
    As[(c4+2)*66 + m] = (double)av.z;
    As[(c4+3)*66 + m] = (double)av.w;
    Bs[k*66 + n4+0] = (double)bv.x;
    Bs[k*66 + n4+1] = (double)bv.y;
    Bs[k*66 + n4+2] = (double)bv.z;
    Bs[k*66 + n4+3] = (double)bv.w;
    __syncthreads();
    #pragma unroll
    for (int kk = 0; kk < 16; ++kk) {
      double av_[4], bv_[4];
      #pragma unroll
      for (int i = 0; i < 4; ++i) { av_[i] = As[kk*66 + ty*4+i]; bv_[i] = Bs[kk*66 + tx*4+i]; }
      #pragma unroll
      for (int i = 0; i < 4; ++i)
        #pragma unroll
        for (int j = 0; j < 4; ++j)
          acc[i][j] = fma(av_[i], bv_[j], acc[i][j]);
    }
    __syncthreads();
  }

  #pragma unroll
  for (int i = 0; i < 4; ++i) {
    int r = m0 + ty*4 + i;
    int b = r >> 11, n = r & (NQ - 1);
    #pragma unroll
    for (int j = 0; j < 4; ++j) {
      int cc = n0 + tx*4 + j;
      int h = cc >> 6, d = cc & 63;
      size_t idx = (((size_t)(b*NHEADS + h))*NQ + n)*64 + d;
      C64[idx] = acc[i][j];
      float v = (float)acc[i][j];
      unsigned short hb = f32_to_bf16_rne(v);
      float hf = __uint_as_float((unsigned)hb << 16);
      unsigned short lb = f32_to_bf16_rne(v - hf);
      Hi[idx] = hb;
      Lo[idx] = lb;
    }
  }
}

// ---------------------------------------------------------------------------
// fp32 GEMM.  MODE 0: +bias, row-major C0[M][N].  MODE 2: scatter V[bh][n][d].
// ---------------------------------------------------------------------------
template<int MODE>
__global__ __launch_bounds__(256) void gemm_f32(
    const float* __restrict__ A, const float* __restrict__ Bm,
    int ldb, int bcoloff, const float* __restrict__ bias,
    float* __restrict__ C0, int M, int N, int K)
{
  __shared__ float As[16*68];
  __shared__ float Bs[16*68];
  const int t  = threadIdx.x;
  const int tx = t & 15, ty = t >> 4;
  const int n0 = blockIdx.x * 64, m0 = blockIdx.y * 64;
  float acc[4][4] = {};

  for (int kt = 0; kt < K; kt += 16) {
    int m  = t >> 2;
    int c4 = (t & 3) * 4;
    const float4 av = *(const float4*)(A + (size_t)(m0 + m) * K + kt + c4);
    As[(c4+0)*68 + m] = av.x;
    As[(c4+1)*68 + m] = av.y;
    As[(c4+2)*68 + m] = av.z;
    As[(c4+3)*68 + m] = av.w;
    int k  = t >> 4;
    int n4 = (t & 15) * 4;
    const float4 bv = *(const float4*)(Bm + (size_t)(kt + k) * ldb + bcoloff + n0 + n4);
    *(float4*)(Bs + k*68 + n4) = bv;
    __syncthreads();
    #pragma unroll
    for (int kk = 0; kk < 16; ++kk) {
      float4 a4 = *(const float4*)(As + kk*68 + ty*4);
      float4 b4 = *(const float4*)(Bs + kk*68 + tx*4);
      float av_[4] = {a4.x, a4.y, a4.z, a4.w};
      float bv_[4] = {b4.x, b4.y, b4.z, b4.w};
      #pragma unroll
      for (int i = 0; i < 4; ++i)
        #pragma unroll
        for (int j = 0; j < 4; ++j)
          acc[i][j] = fmaf(av_[i], bv_[j], acc[i][j]);
    }
    __syncthreads();
  }

  #pragma unroll
  for (int i = 0; i < 4; ++i) {
    int r = m0 + ty*4 + i;
    int b = r >> 11, n = r & (NQ - 1);
    #pragma unroll
    for (int j = 0; j < 4; ++j) {
      int cc = n0 + tx*4 + j;
      if (MODE == 0) {
        C0[(size_t)r * N + cc] = acc[i][j] + bias[cc];
      } else {
        int h = cc >> 6, d = cc & 63;
        C0[(((size_t)(b*NHEADS + h))*NK + n)*64 + d] = acc[i][j];
      }
    }
  }
}

// ---------------------------------------------------------------------------
// Score GEMM via bf16x3 MFMA: S[bh_local][q][k] = 0.125 * (q . k), fp32.
// ---------------------------------------------------------------------------
__global__ __launch_bounds__(256) void score_mfma(
    const unsigned short* __restrict__ Qhi, const unsigned short* __restrict__ Qlo,
    const unsigned short* __restrict__ Khi, const unsigned short* __restrict__ Klo,
    float* __restrict__ S, int bh0)
{
  extern __shared__ unsigned short sm[];
  unsigned short* qh = sm;              // 128*72
  unsigned short* ql = qh + 128*72;
  unsigned short* kh = ql + 128*72;
  unsigned short* kl = kh + 128*72;     // total 73,728 B

  const int t  = threadIdx.x;
  const int qt = blockIdx.x, kt = blockIdx.y;
  const int bh = bh0 + blockIdx.z;
  const size_t qbase = ((size_t)bh*NQ + qt*128) * 64;
  const size_t kbase = ((size_t)bh*NK + kt*128) * 64;

  #pragma unroll
  for (int i = 0; i < 4; ++i) {
    int c   = t + i*256;        // chunk 0..1023 (16 B each)
    int row = c >> 3, off = (c & 7) * 8;
    *(u16x8*)(qh + row*72 + off) = *(const u16x8*)(Qhi + qbase + row*64 + off);
    *(u16x8*)(ql + row*72 + off) = *(const u16x8*)(Qlo + qbase + row*64 + off);
    *(u16x8*)(kh + row*72 + off) = *(const u16x8*)(Khi + kbase + row*64 + off);
    *(u16x8*)(kl + row*72 + off) = *(const u16x8*)(Klo + kbase + row*64 + off);
  }
  __syncthreads();

  const int w = t >> 6, l = t & 63;
  const int quad = l >> 4, lr = l & 15;

  frag_ab aH[2][2], aL[2][2];
  #pragma unroll
  for (int qs = 0; qs < 2; ++qs) {
    int row = w*32 + qs*16 + lr;
    #pragma unroll
    for (int s = 0; s < 2; ++s) {
      aH[qs][s] = *(const frag_ab*)(qh + row*72 + s*32 + quad*8);
      aL[qs][s] = *(const frag_ab*)(ql + row*72 + s*32 + quad*8);
    }
  }

  for (int ks = 0; ks < 8; ++ks) {
    frag_ab bH[2], bL[2];
    int krow = ks*16 + lr;
    #pragma unroll
    for (int s = 0; s < 2; ++s) {
      bH[s] = *(const frag_ab*)(kh + krow*72 + s*32 + quad*8);
      bL[s] = *(const frag_ab*)(kl + krow*72 + s*32 + quad*8);
    }
    #pragma unroll
    for (int qs = 0; qs < 2; ++qs) {
      frag_cd c = {0.f, 0.f, 0.f, 0.f};
      #pragma unroll
      for (int s = 0; s < 2; ++s) {
        c = __builtin_amdgcn_mfma_f32_16x16x32_bf16(aH[qs][s], bH[s], c, 0, 0, 0);
        c = __builtin_amdgcn_mfma_f32_16x16x32_bf16(aH[qs][s], bL[s], c, 0, 0, 0);
        c = __builtin_amdgcn_mfma_f32_16x16x32_bf16(aL[qs][s], bH[s], c, 0, 0, 0);
      }
      int qrow = qt*128 + w*32 + qs*16 + quad*4;   // + i
      int kcol = kt*128 + ks*16 + lr;
      size_t base = ((size_t)blockIdx.z * NQ + qrow) * NK + kcol;
      #pragma unroll
      for (int i = 0; i < 4; ++i)
        S[base + (size_t)i*NK] = c[i] * 0.125f;
    }
  }
}

// ---------------------------------------------------------------------------
// Select: per wave one query row of the chunk. Exact fp32-bits kth via binary
// search, margin collect (skth - 1e-3) -> cand/cnt (global row indexing).
// ---------------------------------------------------------------------------
__global__ __launch_bounds__(256) void select_rows(
    const float* __restrict__ S, unsigned short* __restrict__ cand,
    int* __restrict__ cnt, const int* __restrict__ topkp, int row0)
{
  const int t = threadIdx.x;
  const int w = t >> 6, l = t & 63;
  const int rl = blockIdx.x * 4 + w;
  const size_t row = (size_t)row0 + rl;
  const float* Sr = S + (size_t)rl * NK;
  const unsigned long long lmask = (1ull << l) - 1ull;

  int kEff = *topkp;
  if (kEff > CAND_MAX) kEff = CAND_MAX;
  if (kEff < 1) kEff = 1;

  unsigned uv[32];
  #pragma unroll
  for (int c = 0; c < 32; ++c) {
    unsigned bb = __float_as_uint(Sr[c*64 + l]);
    uv[c] = (bb & 0x80000000u) ? ~bb : (bb | 0x80000000u);
  }
  unsigned lo_ = 0u, hi_ = 0xFFFFFFFFu;
  while (lo_ < hi_) {
    unsigned mid = (unsigned)(((unsigned long long)lo_ + (unsigned long long)hi_ + 1ull) >> 1);
    int c_ = 0;
    #pragma unroll
    for (int c = 0; c < 32; ++c) c_ += (uv[c] >= mid) ? 1 : 0;
    #pragma unroll
    for (int off = 32; off > 0; off >>= 1) c_ += __shfl_xor(c_, off);
    if (c_ >= kEff) lo_ = mid; else hi_ = mid - 1;
  }
  const unsigned uth = lo_;
  float skth = __uint_as_float((uth & 0x80000000u) ? (uth & 0x7FFFFFFFu) : ~uth);
  float smarg = skth - 1e-3f;   // margin >> bf16x3 score err
  unsigned b2 = __float_as_uint(smarg);
  unsigned um = (b2 & 0x80000000u) ? ~b2 : (b2 | 0x80000000u);

  int base = 0;
  for (int c = 0; c < 32; ++c) {
    bool pred = (uv[c] >= um);
    unsigned long long msk = __ballot(pred);
    if (pred) {
      int pos = base + __popcll(msk & lmask);
      if (pos < CAND_MAX) cand[row*CAND_MAX + pos] = (unsigned short)(c*64 + l);
    }
    base += __popcll(msk);
  }
  if (l == 0) cnt[row] = (base < CAND_MAX) ? base : CAND_MAX;
}

// ---------------------------------------------------------------------------
// Phase B: group-coalesced f64 re-score (8 lanes per candidate, 128 B
// contiguous per group per load), exact u64 kth, delta-blend boundary,
// softmax + PV, write inner.
// ---------------------------------------------------------------------------
__global__ __launch_bounds__(256) void attn_phase_b(
    const double* __restrict__ Q64, const double* __restrict__ K64,
    const float* __restrict__ V32, const unsigned short* __restrict__ cand,
    const int* __restrict__ cnt, float* __restrict__ inner,
    const int* __restrict__ topkp)
{
  const int t = threadIdx.x;
  const int w = t >> 6, l = t & 63;
  const size_t row = (size_t)blockIdx.x * 4 + w;
  const int bh = (int)(row >> 11);
  const int q  = (int)(row & (NQ - 1));
  const unsigned long long lmask = (1ull << l) - 1ull;

  int kEff = *topkp;
  if (kEff > CAND_MAX) kEff = CAND_MAX;
  if (kEff < 1) kEff = 1;
  int m = cnt[row];
  if (kEff > m) kEff = m;

  const double* Kb = K64 + (size_t)bh * NK * 64;
  const float*  Vb = V32 + (size_t)bh * NK * 64;

  const int g = l >> 3, r = l & 7;   // group, rank-in-group
  // lane's fixed q-slots: doubles [i*16 + r*2, +2) for i=0..3
  double2 q2[4];
  #pragma unroll
  for (int i = 0; i < 4; ++i)
    q2[i] = *(const double2*)(Q64 + row*64 + i*16 + r*2);

  int ck[2];
  ck[0] = cand[row*CAND_MAX + l];
  ck[1] = cand[row*CAND_MAX + 64 + l];
  double cs[2] = {-INFINITY, -INFINITY};
  unsigned long long cu[2] = {0ull, 0ull};

  const int npass = (m > 64) ? 16 : 8;   // wave-uniform
  for (int p = 0; p < npass; ++p) {
    const int j = p*8 + g;               // candidate index this group computes
    const bool valid = (j < m);
    int key = __shfl(ck[p >> 3], j & 63);
    const double* kp = Kb + (size_t)(valid ? key : 0) * 64;
    double s0 = 0.0, s1 = 0.0;
    #pragma unroll
    for (int i = 0; i < 4; ++i) {
      double2 kv = *(const double2*)(kp + i*16 + r*2);
      s0 = fma(kv.x, q2[i].x, s0);
      s1 = fma(kv.y, q2[i].y, s1);
    }
    double s = s0 + s1;
    s += __shfl_xor(s, 1);
    s += __shfl_xor(s, 2);
    s += __shfl_xor(s, 4);               // all 8 lanes of group hold dot
    s *= 0.125;
    // owner lane for candidate (p&7)*8 + (l&7) is l with (l>>3)==(p&7)
    double sc = __shfl(s, (l & 7) * 8);
    const int pp = p & 7, c = p >> 3;
    if ((l >> 3) == pp && (c*64 + pp*8 + (l & 7)) < m) {
      unsigned long long b = (unsigned long long)__double_as_longlong(sc);
      cs[c] = sc;
      cu[c] = (b >> 63) ? ~b : (b | 0x8000000000000000ull);
    }
  }

  // exact kth largest u64
  unsigned long long T = 0ull;
  if (m > 64) {
    for (int bit = 63; bit >= 0; --bit) {
      unsigned long long cT = T | (1ull << bit);
      int tot = __popcll(__ballot(cu[0] >= cT)) + __popcll(__ballot(cu[1] >= cT));
      if (tot >= kEff) T = cT;
    }
  } else {
    for (int bit = 63; bit >= 0; --bit) {
      unsigned long long cT = T | (1ull << bit);
      int tot = __popcll(__ballot(cu[0] >= cT));
      if (tot >= kEff) T = cT;
    }
  }
  double s_kth;
  { unsigned long long bb = (T >> 63) ? (T & 0x7FFFFFFFFFFFFFFFull) : ~T;
    s_kth = __longlong_as_double((long long)bb); }

  double nx = -INFINITY;
  #pragma unroll
  for (int c = 0; c < 2; ++c) { double v = (cu[c] < T) ? cs[c] : -INFINITY; nx = fmax(nx, v); }
  #pragma unroll
  for (int off = 32; off > 0; off >>= 1) nx = fmax(nx, __shfl_xor(nx, off));

  double smax = fmax(cs[0], cs[1]);
  #pragma unroll
  for (int off = 32; off > 0; off >>= 1) smax = fmax(smax, __shfl_xor(smax, off));

  const double DELTA = 5e-6;
  float wgt[2];
  if (!(s_kth - nx < 2.0*DELTA)) {
    int cgt = __popcll(__ballot(cu[0] > T)) + __popcll(__ballot(cu[1] > T));
    int nEq = kEff - cgt;
    int eqBase = 0;
    #pragma unroll
    for (int c = 0; c < 2; ++c) {
      bool eq = (cu[c] == T);
      unsigned long long eqm = __ballot(eq);
      int er = __popcll(eqm & lmask);
      bool sel = (cu[c] > T) || (eq && (eqBase + er) < nEq);
      eqBase += __popcll(eqm);
      wgt[c] = sel ? (float)exp(cs[c] - smax) : 0.f;
    }
  } else {
    double cmid = 0.5 * (s_kth + nx);
    #pragma unroll
    for (int c = 0; c < 2; ++c) {
      double mu = 0.5 + (cs[c] - cmid) / (2.0*DELTA);
      mu = fmin(1.0, fmax(0.0, mu));
      wgt[c] = (float)(mu * exp(cs[c] - smax));
    }
  }

  float acc = 0.f, wsum = 0.f;
  for (int j = 0; j < m; ++j) {
    int c = j >> 6;
    float wj = __shfl(wgt[c], j & 63);
    if (wj != 0.f) {
      int key = __shfl(ck[c], j & 63);
      wsum += wj;
      acc = fmaf(wj, Vb[(size_t)key*64 + l], acc);
    }
  }
  int b = bh >> 3, h = bh & 7;
  inner[((size_t)b*NQ + q)*INNER + h*DHEAD + l] = acc / wsum;
}

// ---------------------------------------------------------------------------
extern "C" void kernel_launch(void* const* d_in, const int* in_sizes, int n_in,
                              void* d_out, int out_size, void* d_ws, size_t ws_size,
                              hipStream_t stream)
{
  const float* x    = (const float*)d_in[0];
  const float* ctx  = (const float*)d_in[1];
  const float* Wq   = (const float*)d_in[2];
  const float* Wkv  = (const float*)d_in[3];
  const float* Wout = (const float*)d_in[4];
  const float* bout = (const float*)d_in[5];
  const int*   topk = (const int*)d_in[6];
  float* out = (float*)d_out;

  const size_t SZ = (size_t)BATCH * NHEADS * NQ * DHEAD;  // 4,194,304

  // ---- ws layout (fixed 112.5 MB) + adaptive score slab + aliasing ----
  size_t off = 0;
  char* base = (char*)d_ws;
  auto take = [&](size_t bytes) { char* r = base + off; off += (bytes + 255) & ~(size_t)255; return r; };
  double* Q64 = (double*)take(SZ * sizeof(double));                        // 32 MB
  double* K64 = (double*)take(SZ * sizeof(double));                        // 32 MB
  unsigned short* cand = (unsigned short*)take((size_t)NROWS * CAND_MAX * 2); // 16 MB
  int* cnt = (int*)take((size_t)NROWS * sizeof(int));                      // 256 KB
  unsigned short* Qhi = (unsigned short*)take(SZ * 2);                     // 8 MB
  unsigned short* Qlo = (unsigned short*)take(SZ * 2);                     // 8 MB
  unsigned short* Khi = (unsigned short*)take(SZ * 2);                     // 8 MB
  unsigned short* Klo = (unsigned short*)take(SZ * 2);                     // 8 MB
  float* S = (float*)(base + off);          // remainder: score slab
  // Aliases (live only after score/select complete):
  float* V32   = (float*)Qhi;               // 16 MB over Qhi+Qlo
  float* inner = (float*)Khi;               // 16 MB over Khi+Klo

  const size_t per_bh = (size_t)NQ * NK * sizeof(float);  // 16 MB
  size_t avail = (ws_size > off) ? (ws_size - off) : 0;
  int bhchunk = (int)(avail / per_bh);
  if (bhchunk < 1)  bhchunk = 1;     // (requires ws_size >= ~128.5 MB)
  if (bhchunk > 32) bhchunk = 32;

  const int M = BATCH * NQ;  // 8192
  const int SCORE_LDS = 4 * 128 * 72 * (int)sizeof(unsigned short); // 73,728 B
  hipFuncSetAttribute(reinterpret_cast<const void*>(score_mfma),
                      hipFuncAttributeMaxDynamicSharedMemorySize, SCORE_LDS);

  gemm_f64_proj<<<dim3(INNER/64, M/64), 256, 0, stream>>>(x,   Wq,  INNER,   0, Q64, Qhi, Qlo);
  gemm_f64_proj<<<dim3(INNER/64, M/64), 256, 0, stream>>>(ctx, Wkv, 2*INNER, 0, K64, Khi, Klo);

  for (int c0 = 0; c0 < BATCH*NHEADS; c0 += bhchunk) {
    int cc = BATCH*NHEADS - c0; if (cc > bhchunk) cc = bhchunk;
    score_mfma<<<dim3(NQ/128, NK/128, cc), 256, SCORE_LDS, stream>>>(
        Qhi, Qlo, Khi, Klo, S, c0);
    select_rows<<<dim3(cc*NQ/4), 256, 0, stream>>>(S, cand, cnt, topk, c0*NQ);
  }

  // V32 overwrites Qhi/Qlo (dead), inner overwrites Khi/Klo (dead).
  gemm_f32<2><<<dim3(INNER/64, M/64), 256, 0, stream>>>(ctx, Wkv, 2*INNER, INNER, nullptr, V32, M, INNER, DQ);
  attn_phase_b<<<dim3(NROWS/4), 256, 0, stream>>>(Q64, K64, V32, cand, cnt, inner, topk);
  gemm_f32<0><<<dim3(DQ/64, M/64), 256, 0, stream>>>(inner, Wout, DQ, 0, bout, out, M, DQ, INNER);
}

// Round 10
// 1573.745 us; speedup vs baseline: 2.1836x; 1.1072x over previous
//
#include <hip/hip_runtime.h>
#include <math.h>

#define BATCH 4
#define NQ 2048
#define NK 2048
#define DQ 1024
#define NHEADS 8
#define DHEAD 64
#define INNER (NHEADS*DHEAD)     // 512
#define NROWS (BATCH*NHEADS*NQ)  // 65536
#define CAND_MAX 128

using frag_ab = __attribute__((ext_vector_type(8))) short;   // 8 bf16
using frag_cd = __attribute__((ext_vector_type(4))) float;   // 4 fp32
using u16x8   = __attribute__((ext_vector_type(8))) unsigned short;

static __device__ __forceinline__ unsigned short f32_to_bf16_rne(float f) {
  unsigned u = __float_as_uint(f);
  u += 0x7FFFu + ((u >> 16) & 1u);
  return (unsigned short)(u >> 16);
}

// ---------------------------------------------------------------------------
// f64-accumulate projection GEMM, f32 LDS staging (conflict-free, half the
// LDS bytes of round-8's f64 staging; same FMA order => bit-identical C64).
// C64[bh][n][d] scatter + bf16 hi/lo split epilogue.
// ---------------------------------------------------------------------------
__global__ __launch_bounds__(256) void gemm_f64_proj(
    const float* __restrict__ A, const float* __restrict__ Bm,
    int ldb, int bcoloff, double* __restrict__ C64,
    unsigned short* __restrict__ Hi, unsigned short* __restrict__ Lo)
{
  __shared__ float As[16*68];  // [k][m], pad 68 (stride 4 words per tx-step)
  __shared__ float Bs[16*68];  // [k][n]
  const int t  = threadIdx.x;
  const int tx = t & 15, ty = t >> 4;
  const int n0 = blockIdx.x * 64, m0 = blockIdx.y * 64;
  double acc[4][4] = {};

  for (int kt = 0; kt < DQ; kt += 16) {
    {
      int m  = t >> 2;
      int c4 = (t & 3) * 4;
      const float4 av = *(const float4*)(A + (size_t)(m0 + m) * DQ + kt + c4);
      As[(c4+0)*68 + m] = av.x;
      As[(c4+1)*68 + m] = av.y;
      As[(c4+2)*68 + m] = av.z;
      As[(c4+3)*68 + m] = av.w;
      int k  = t >> 4;
      int n4 = (t & 15) * 4;
      const float4 bv = *(const float4*)(Bm + (size_t)(kt + k) * ldb + bcoloff + n0 + n4);
      *(float4*)(Bs + k*68 + n4) = bv;
    }
    __syncthreads();
    #pragma unroll
    for (int kk = 0; kk < 16; ++kk) {
      float4 a4 = *(const float4*)(As + kk*68 + ty*4);
      float4 b4 = *(const float4*)(Bs + kk*68 + tx*4);
      double ad[4] = {(double)a4.x, (double)a4.y, (double)a4.z, (double)a4.w};
      double bd[4] = {(double)b4.x, (double)b4.y, (double)b4.z, (double)b4.w};
      #pragma unroll
      for (int i = 0; i < 4; ++i)
        #pragma unroll
        for (int j = 0; j < 4; ++j)
          acc[i][j] = fma(ad[i], bd[j], acc[i][j]);
    }
    __syncthreads();
  }

  #pragma unroll
  for (int i = 0; i < 4; ++i) {
    int r = m0 + ty*4 + i;
    int b = r >> 11, n = r & (NQ - 1);
    #pragma unroll
    for (int j = 0; j < 4; ++j) {
      int cc = n0 + tx*4 + j;
      int h = cc >> 6, d = cc & 63;
      size_t idx = (((size_t)(b*NHEADS + h))*NQ + n)*64 + d;
      double v = acc[i][j];
      C64[idx] = v;
      float vf = (float)v;
      unsigned short hb = f32_to_bf16_rne(vf);
      float hf = __uint_as_float((unsigned)hb << 16);
      unsigned short lb = f32_to_bf16_rne(vf - hf);
      Hi[idx] = hb;
      Lo[idx] = lb;
    }
  }
}

// ---------------------------------------------------------------------------
// fp32 GEMM.  MODE 0: +bias, row-major C0[M][N].  MODE 2: scatter V[bh][n][d].
// ---------------------------------------------------------------------------
template<int MODE>
__global__ __launch_bounds__(256) void gemm_f32(
    const float* __restrict__ A, const float* __restrict__ Bm,
    int ldb, int bcoloff, const float* __restrict__ bias,
    float* __restrict__ C0, int M, int N, int K)
{
  __shared__ float As[16*68];
  __shared__ float Bs[16*68];
  const int t  = threadIdx.x;
  const int tx = t & 15, ty = t >> 4;
  const int n0 = blockIdx.x * 64, m0 = blockIdx.y * 64;
  float acc[4][4] = {};

  for (int kt = 0; kt < K; kt += 16) {
    int m  = t >> 2;
    int c4 = (t & 3) * 4;
    const float4 av = *(const float4*)(A + (size_t)(m0 + m) * K + kt + c4);
    As[(c4+0)*68 + m] = av.x;
    As[(c4+1)*68 + m] = av.y;
    As[(c4+2)*68 + m] = av.z;
    As[(c4+3)*68 + m] = av.w;
    int k  = t >> 4;
    int n4 = (t & 15) * 4;
    const float4 bv = *(const float4*)(Bm + (size_t)(kt + k) * ldb + bcoloff + n0 + n4);
    *(float4*)(Bs + k*68 + n4) = bv;
    __syncthreads();
    #pragma unroll
    for (int kk = 0; kk < 16; ++kk) {
      float4 a4 = *(const float4*)(As + kk*68 + ty*4);
      float4 b4 = *(const float4*)(Bs + kk*68 + tx*4);
      float av_[4] = {a4.x, a4.y, a4.z, a4.w};
      float bv_[4] = {b4.x, b4.y, b4.z, b4.w};
      #pragma unroll
      for (int i = 0; i < 4; ++i)
        #pragma unroll
        for (int j = 0; j < 4; ++j)
          acc[i][j] = fmaf(av_[i], bv_[j], acc[i][j]);
    }
    __syncthreads();
  }

  #pragma unroll
  for (int i = 0; i < 4; ++i) {
    int r = m0 + ty*4 + i;
    int b = r >> 11, n = r & (NQ - 1);
    #pragma unroll
    for (int j = 0; j < 4; ++j) {
      int cc = n0 + tx*4 + j;
      if (MODE == 0) {
        C0[(size_t)r * N + cc] = acc[i][j] + bias[cc];
      } else {
        int h = cc >> 6, d = cc & 63;
        C0[(((size_t)(b*NHEADS + h))*NK + n)*64 + d] = acc[i][j];
      }
    }
  }
}

// ---------------------------------------------------------------------------
// Score GEMM via bf16x3 MFMA: S[bh_local][q][k] = 0.125 * (q . k), fp32.
// ---------------------------------------------------------------------------
__global__ __launch_bounds__(256) void score_mfma(
    const unsigned short* __restrict__ Qhi, const unsigned short* __restrict__ Qlo,
    const unsigned short* __restrict__ Khi, const unsigned short* __restrict__ Klo,
    float* __restrict__ S, int bh0)
{
  extern __shared__ unsigned short sm[];
  unsigned short* qh = sm;              // 128*72
  unsigned short* ql = qh + 128*72;
  unsigned short* kh = ql + 128*72;
  unsigned short* kl = kh + 128*72;     // total 73,728 B

  const int t  = threadIdx.x;
  const int qt = blockIdx.x, kt = blockIdx.y;
  const int bh = bh0 + blockIdx.z;
  const size_t qbase = ((size_t)bh*NQ + qt*128) * 64;
  const size_t kbase = ((size_t)bh*NK + kt*128) * 64;

  #pragma unroll
  for (int i = 0; i < 4; ++i) {
    int c   = t + i*256;        // chunk 0..1023 (16 B each)
    int row = c >> 3, off = (c & 7) * 8;
    *(u16x8*)(qh + row*72 + off) = *(const u16x8*)(Qhi + qbase + row*64 + off);
    *(u16x8*)(ql + row*72 + off) = *(const u16x8*)(Qlo + qbase + row*64 + off);
    *(u16x8*)(kh + row*72 + off) = *(const u16x8*)(Khi + kbase + row*64 + off);
    *(u16x8*)(kl + row*72 + off) = *(const u16x8*)(Klo + kbase + row*64 + off);
  }
  __syncthreads();

  const int w = t >> 6, l = t & 63;
  const int quad = l >> 4, lr = l & 15;

  frag_ab aH[2][2], aL[2][2];
  #pragma unroll
  for (int qs = 0; qs < 2; ++qs) {
    int row = w*32 + qs*16 + lr;
    #pragma unroll
    for (int s = 0; s < 2; ++s) {
      aH[qs][s] = *(const frag_ab*)(qh + row*72 + s*32 + quad*8);
      aL[qs][s] = *(const frag_ab*)(ql + row*72 + s*32 + quad*8);
    }
  }

  for (int ks = 0; ks < 8; ++ks) {
    frag_ab bH[2], bL[2];
    int krow = ks*16 + lr;
    #pragma unroll
    for (int s = 0; s < 2; ++s) {
      bH[s] = *(const frag_ab*)(kh + krow*72 + s*32 + quad*8);
      bL[s] = *(const frag_ab*)(kl + krow*72 + s*32 + quad*8);
    }
    #pragma unroll
    for (int qs = 0; qs < 2; ++qs) {
      frag_cd c = {0.f, 0.f, 0.f, 0.f};
      #pragma unroll
      for (int s = 0; s < 2; ++s) {
        c = __builtin_amdgcn_mfma_f32_16x16x32_bf16(aH[qs][s], bH[s], c, 0, 0, 0);
        c = __builtin_amdgcn_mfma_f32_16x16x32_bf16(aH[qs][s], bL[s], c, 0, 0, 0);
        c = __builtin_amdgcn_mfma_f32_16x16x32_bf16(aL[qs][s], bH[s], c, 0, 0, 0);
      }
      int qrow = qt*128 + w*32 + qs*16 + quad*4;   // + i
      int kcol = kt*128 + ks*16 + lr;
      size_t base = ((size_t)blockIdx.z * NQ + qrow) * NK + kcol;
      #pragma unroll
      for (int i = 0; i < 4; ++i)
        S[base + (size_t)i*NK] = c[i] * 0.125f;
    }
  }
}

// ---------------------------------------------------------------------------
// Select: per wave one query row of the chunk. Exact fp32-bits kth via binary
// search, margin collect (skth - 1e-3) -> cand/cnt (global row indexing).
// ---------------------------------------------------------------------------
__global__ __launch_bounds__(256) void select_rows(
    const float* __restrict__ S, unsigned short* __restrict__ cand,
    int* __restrict__ cnt, const int* __restrict__ topkp, int row0)
{
  const int t = threadIdx.x;
  const int w = t >> 6, l = t & 63;
  const int rl = blockIdx.x * 4 + w;
  const size_t row = (size_t)row0 + rl;
  const float* Sr = S + (size_t)rl * NK;
  const unsigned long long lmask = (1ull << l) - 1ull;

  int kEff = *topkp;
  if (kEff > CAND_MAX) kEff = CAND_MAX;
  if (kEff < 1) kEff = 1;

  unsigned uv[32];
  #pragma unroll
  for (int c = 0; c < 32; ++c) {
    unsigned bb = __float_as_uint(Sr[c*64 + l]);
    uv[c] = (bb & 0x80000000u) ? ~bb : (bb | 0x80000000u);
  }
  unsigned lo_ = 0u, hi_ = 0xFFFFFFFFu;
  while (lo_ < hi_) {
    unsigned mid = (unsigned)(((unsigned long long)lo_ + (unsigned long long)hi_ + 1ull) >> 1);
    int c_ = 0;
    #pragma unroll
    for (int c = 0; c < 32; ++c) c_ += (uv[c] >= mid) ? 1 : 0;
    #pragma unroll
    for (int off = 32; off > 0; off >>= 1) c_ += __shfl_xor(c_, off);
    if (c_ >= kEff) lo_ = mid; else hi_ = mid - 1;
  }
  const unsigned uth = lo_;
  float skth = __uint_as_float((uth & 0x80000000u) ? (uth & 0x7FFFFFFFu) : ~uth);
  float smarg = skth - 1e-3f;   // margin >> bf16x3 score err
  unsigned b2 = __float_as_uint(smarg);
  unsigned um = (b2 & 0x80000000u) ? ~b2 : (b2 | 0x80000000u);

  int base = 0;
  for (int c = 0; c < 32; ++c) {
    bool pred = (uv[c] >= um);
    unsigned long long msk = __ballot(pred);
    if (pred) {
      int pos = base + __popcll(msk & lmask);
      if (pos < CAND_MAX) cand[row*CAND_MAX + pos] = (unsigned short)(c*64 + l);
    }
    base += __popcll(msk);
  }
  if (l == 0) cnt[row] = (base < CAND_MAX) ? base : CAND_MAX;
}

// ---------------------------------------------------------------------------
// Phase B: group-coalesced f64 re-score (8 lanes per candidate, 128 B
// contiguous per group per load), exact u64 kth, delta-blend boundary,
// softmax + PV, write inner.
// ---------------------------------------------------------------------------
__global__ __launch_bounds__(256) void attn_phase_b(
    const double* __restrict__ Q64, const double* __restrict__ K64,
    const float* __restrict__ V32, const unsigned short* __restrict__ cand,
    const int* __restrict__ cnt, float* __restrict__ inner,
    const int* __restrict__ topkp)
{
  const int t = threadIdx.x;
  const int w = t >> 6, l = t & 63;
  const size_t row = (size_t)blockIdx.x * 4 + w;
  const int bh = (int)(row >> 11);
  const int q  = (int)(row & (NQ - 1));
  const unsigned long long lmask = (1ull << l) - 1ull;

  int kEff = *topkp;
  if (kEff > CAND_MAX) kEff = CAND_MAX;
  if (kEff < 1) kEff = 1;
  int m = cnt[row];
  if (kEff > m) kEff = m;

  const double* Kb = K64 + (size_t)bh * NK * 64;
  const float*  Vb = V32 + (size_t)bh * NK * 64;

  const int g = l >> 3, r = l & 7;   // group, rank-in-group
  double2 q2[4];
  #pragma unroll
  for (int i = 0; i < 4; ++i)
    q2[i] = *(const double2*)(Q64 + row*64 + i*16 + r*2);

  int ck[2];
  ck[0] = cand[row*CAND_MAX + l];
  ck[1] = cand[row*CAND_MAX + 64 + l];
  double cs[2] = {-INFINITY, -INFINITY};
  unsigned long long cu[2] = {0ull, 0ull};

  const int npass = (m > 64) ? 16 : 8;   // wave-uniform
  for (int p = 0; p < npass; ++p) {
    const int j = p*8 + g;               // candidate index this group computes
    const bool valid = (j < m);
    int key = __shfl(ck[p >> 3], j & 63);
    const double* kp = Kb + (size_t)(valid ? key : 0) * 64;
    double s0 = 0.0, s1 = 0.0;
    #pragma unroll
    for (int i = 0; i < 4; ++i) {
      double2 kv = *(const double2*)(kp + i*16 + r*2);
      s0 = fma(kv.x, q2[i].x, s0);
      s1 = fma(kv.y, q2[i].y, s1);
    }
    double s = s0 + s1;
    s += __shfl_xor(s, 1);
    s += __shfl_xor(s, 2);
    s += __shfl_xor(s, 4);               // all 8 lanes of group hold dot
    s *= 0.125;
    double sc = __shfl(s, (l & 7) * 8);
    const int pp = p & 7, c = p >> 3;
    if ((l >> 3) == pp && (c*64 + pp*8 + (l & 7)) < m) {
      unsigned long long b = (unsigned long long)__double_as_longlong(sc);
      cs[c] = sc;
      cu[c] = (b >> 63) ? ~b : (b | 0x8000000000000000ull);
    }
  }

  // exact kth largest u64
  unsigned long long T = 0ull;
  if (m > 64) {
    for (int bit = 63; bit >= 0; --bit) {
      unsigned long long cT = T | (1ull << bit);
      int tot = __popcll(__ballot(cu[0] >= cT)) + __popcll(__ballot(cu[1] >= cT));
      if (tot >= kEff) T = cT;
    }
  } else {
    for (int bit = 63; bit >= 0; --bit) {
      unsigned long long cT = T | (1ull << bit);
      int tot = __popcll(__ballot(cu[0] >= cT));
      if (tot >= kEff) T = cT;
    }
  }
  double s_kth;
  { unsigned long long bb = (T >> 63) ? (T & 0x7FFFFFFFFFFFFFFFull) : ~T;
    s_kth = __longlong_as_double((long long)bb); }

  double nx = -INFINITY;
  #pragma unroll
  for (int c = 0; c < 2; ++c) { double v = (cu[c] < T) ? cs[c] : -INFINITY; nx = fmax(nx, v); }
  #pragma unroll
  for (int off = 32; off > 0; off >>= 1) nx = fmax(nx, __shfl_xor(nx, off));

  double smax = fmax(cs[0], cs[1]);
  #pragma unroll
  for (int off = 32; off > 0; off >>= 1) smax = fmax(smax, __shfl_xor(smax, off));

  const double DELTA = 5e-6;
  float wgt[2];
  if (!(s_kth - nx < 2.0*DELTA)) {
    int cgt = __popcll(__ballot(cu[0] > T)) + __popcll(__ballot(cu[1] > T));
    int nEq = kEff - cgt;
    int eqBase = 0;
    #pragma unroll
    for (int c = 0; c < 2; ++c) {
      bool eq = (cu[c] == T);
      unsigned long long eqm = __ballot(eq);
      int er = __popcll(eqm & lmask);
      bool sel = (cu[c] > T) || (eq && (eqBase + er) < nEq);
      eqBase += __popcll(eqm);
      wgt[c] = sel ? (float)exp(cs[c] - smax) : 0.f;
    }
  } else {
    double cmid = 0.5 * (s_kth + nx);
    #pragma unroll
    for (int c = 0; c < 2; ++c) {
      double mu = 0.5 + (cs[c] - cmid) / (2.0*DELTA);
      mu = fmin(1.0, fmax(0.0, mu));
      wgt[c] = (float)(mu * exp(cs[c] - smax));
    }
  }

  float acc = 0.f, wsum = 0.f;
  for (int j = 0; j < m; ++j) {
    int c = j >> 6;
    float wj = __shfl(wgt[c], j & 63);
    if (wj != 0.f) {
      int key = __shfl(ck[c], j & 63);
      wsum += wj;
      acc = fmaf(wj, Vb[(size_t)key*64 + l], acc);
    }
  }
  int b = bh >> 3, h = bh & 7;
  inner[((size_t)b*NQ + q)*INNER + h*DHEAD + l] = acc / wsum;
}

// ---------------------------------------------------------------------------
extern "C" void kernel_launch(void* const* d_in, const int* in_sizes, int n_in,
                              void* d_out, int out_size, void* d_ws, size_t ws_size,
                              hipStream_t stream)
{
  const float* x    = (const float*)d_in[0];
  const float* ctx  = (const float*)d_in[1];
  const float* Wq   = (const float*)d_in[2];
  const float* Wkv  = (const float*)d_in[3];
  const float* Wout = (const float*)d_in[4];
  const float* bout = (const float*)d_in[5];
  const int*   topk = (const int*)d_in[6];
  float* out = (float*)d_out;

  const size_t SZ = (size_t)BATCH * NHEADS * NQ * DHEAD;  // 4,194,304

  // ---- ws layout (fixed 112.5 MB) + adaptive score slab + aliasing ----
  size_t off = 0;
  char* base = (char*)d_ws;
  auto take = [&](size_t bytes) { char* r = base + off; off += (bytes + 255) & ~(size_t)255; return r; };
  double* Q64 = (double*)take(SZ * sizeof(double));                        // 32 MB
  double* K64 = (double*)take(SZ * sizeof(double));                        // 32 MB
  unsigned short* cand = (unsigned short*)take((size_t)NROWS * CAND_MAX * 2); // 16 MB
  int* cnt = (int*)take((size_t)NROWS * sizeof(int));                      // 256 KB
  unsigned short* Qhi = (unsigned short*)take(SZ * 2);                     // 8 MB
  unsigned short* Qlo = (unsigned short*)take(SZ * 2);                     // 8 MB
  unsigned short* Khi = (unsigned short*)take(SZ * 2);                     // 8 MB
  unsigned short* Klo = (unsigned short*)take(SZ * 2);                     // 8 MB
  float* S = (float*)(base + off);          // remainder: score slab
  // Aliases (live only after score/select complete):
  float* V32   = (float*)Qhi;               // 16 MB over Qhi+Qlo
  float* inner = (float*)Khi;               // 16 MB over Khi+Klo

  const size_t per_bh = (size_t)NQ * NK * sizeof(float);  // 16 MB
  size_t avail = (ws_size > off) ? (ws_size - off) : 0;
  int bhchunk = (int)(avail / per_bh);
  if (bhchunk < 1)  bhchunk = 1;     // (requires ws_size >= ~128.5 MB)
  if (bhchunk > 32) bhchunk = 32;

  const int M = BATCH * NQ;  // 8192
  const int SCORE_LDS = 4 * 128 * 72 * (int)sizeof(unsigned short); // 73,728 B
  hipFuncSetAttribute(reinterpret_cast<const void*>(score_mfma),
                      hipFuncAttributeMaxDynamicSharedMemorySize, SCORE_LDS);

  gemm_f64_proj<<<dim3(INNER/64, M/64), 256, 0, stream>>>(x,   Wq,  INNER,   0, Q64, Qhi, Qlo);
  gemm_f64_proj<<<dim3(INNER/64, M/64), 256, 0, stream>>>(ctx, Wkv, 2*INNER, 0, K64, Khi, Klo);

  for (int c0 = 0; c0 < BATCH*NHEADS; c0 += bhchunk) {
    int cc = BATCH*NHEADS - c0; if (cc > bhchunk) cc = bhchunk;
    score_mfma<<<dim3(NQ/128, NK/128, cc), 256, SCORE_LDS, stream>>>(
        Qhi, Qlo, Khi, Klo, S, c0);
    select_rows<<<dim3(cc*NQ/4), 256, 0, stream>>>(S, cand, cnt, topk, c0*NQ);
  }

  // V32 overwrites Qhi/Qlo (dead), inner overwrites Khi/Klo (dead).
  gemm_f32<2><<<dim3(INNER/64, M/64), 256, 0, stream>>>(ctx, Wkv, 2*INNER, INNER, nullptr, V32, M, INNER, DQ);
  attn_phase_b<<<dim3(NROWS/4), 256, 0, stream>>>(Q64, K64, V32, cand, cnt, inner, topk);
  gemm_f32<0><<<dim3(DQ/64, M/64), 256, 0, stream>>>(inner, Wout, DQ, 0, bout, out, M, DQ, INNER);
}

// Round 11
// 1376.613 us; speedup vs baseline: 2.4963x; 1.1432x over previous
//
#include <hip/hip_runtime.h>
#include <math.h>

#define BATCH 4
#define NQ 2048
#define NK 2048
#define DQ 1024
#define NHEADS 8
#define DHEAD 64
#define INNER (NHEADS*DHEAD)     // 512
#define NROWS (BATCH*NHEADS*NQ)  // 65536
#define CAND_MAX 128

using frag_ab = __attribute__((ext_vector_type(8))) short;   // 8 bf16
using frag_cd = __attribute__((ext_vector_type(4))) float;   // 4 fp32
using u16x8   = __attribute__((ext_vector_type(8))) unsigned short;

static __device__ __forceinline__ unsigned short f32_to_bf16_rne(float f) {
  unsigned u = __float_as_uint(f);
  u += 0x7FFFu + ((u >> 16) & 1u);
  return (unsigned short)(u >> 16);
}

// ---------------------------------------------------------------------------
// f64-accumulate projection GEMM, f32 LDS staging (conflict-free).
// C64[bh][n][d] scatter + bf16 hi/lo split epilogue.
// ---------------------------------------------------------------------------
__global__ __launch_bounds__(256) void gemm_f64_proj(
    const float* __restrict__ A, const float* __restrict__ Bm,
    int ldb, int bcoloff, double* __restrict__ C64,
    unsigned short* __restrict__ Hi, unsigned short* __restrict__ Lo)
{
  __shared__ float As[16*68];  // [k][m]
  __shared__ float Bs[16*68];  // [k][n]
  const int t  = threadIdx.x;
  const int tx = t & 15, ty = t >> 4;
  const int n0 = blockIdx.x * 64, m0 = blockIdx.y * 64;
  double acc[4][4] = {};

  for (int kt = 0; kt < DQ; kt += 16) {
    {
      int m  = t >> 2;
      int c4 = (t & 3) * 4;
      const float4 av = *(const float4*)(A + (size_t)(m0 + m) * DQ + kt + c4);
      As[(c4+0)*68 + m] = av.x;
      As[(c4+1)*68 + m] = av.y;
      As[(c4+2)*68 + m] = av.z;
      As[(c4+3)*68 + m] = av.w;
      int k  = t >> 4;
      int n4 = (t & 15) * 4;
      const float4 bv = *(const float4*)(Bm + (size_t)(kt + k) * ldb + bcoloff + n0 + n4);
      *(float4*)(Bs + k*68 + n4) = bv;
    }
    __syncthreads();
    #pragma unroll
    for (int kk = 0; kk < 16; ++kk) {
      float4 a4 = *(const float4*)(As + kk*68 + ty*4);
      float4 b4 = *(const float4*)(Bs + kk*68 + tx*4);
      double ad[4] = {(double)a4.x, (double)a4.y, (double)a4.z, (double)a4.w};
      double bd[4] = {(double)b4.x, (double)b4.y, (double)b4.z, (double)b4.w};
      #pragma unroll
      for (int i = 0; i < 4; ++i)
        #pragma unroll
        for (int j = 0; j < 4; ++j)
          acc[i][j] = fma(ad[i], bd[j], acc[i][j]);
    }
    __syncthreads();
  }

  #pragma unroll
  for (int i = 0; i < 4; ++i) {
    int r = m0 + ty*4 + i;
    int b = r >> 11, n = r & (NQ - 1);
    #pragma unroll
    for (int j = 0; j < 4; ++j) {
      int cc = n0 + tx*4 + j;
      int h = cc >> 6, d = cc & 63;
      size_t idx = (((size_t)(b*NHEADS + h))*NQ + n)*64 + d;
      double v = acc[i][j];
      C64[idx] = v;
      float vf = (float)v;
      unsigned short hb = f32_to_bf16_rne(vf);
      float hf = __uint_as_float((unsigned)hb << 16);
      unsigned short lb = f32_to_bf16_rne(vf - hf);
      Hi[idx] = hb;
      Lo[idx] = lb;
    }
  }
}

// ---------------------------------------------------------------------------
// fp32 GEMM.  MODE 0: +bias, row-major C0[M][N].  MODE 2: scatter V[bh][n][d].
// ---------------------------------------------------------------------------
template<int MODE>
__global__ __launch_bounds__(256) void gemm_f32(
    const float* __restrict__ A, const float* __restrict__ Bm,
    int ldb, int bcoloff, const float* __restrict__ bias,
    float* __restrict__ C0, int M, int N, int K)
{
  __shared__ float As[16*68];
  __shared__ float Bs[16*68];
  const int t  = threadIdx.x;
  const int tx = t & 15, ty = t >> 4;
  const int n0 = blockIdx.x * 64, m0 = blockIdx.y * 64;
  float acc[4][4] = {};

  for (int kt = 0; kt < K; kt += 16) {
    int m  = t >> 2;
    int c4 = (t & 3) * 4;
    const float4 av = *(const float4*)(A + (size_t)(m0 + m) * K + kt + c4);
    As[(c4+0)*68 + m] = av.x;
    As[(c4+1)*68 + m] = av.y;
    As[(c4+2)*68 + m] = av.z;
    As[(c4+3)*68 + m] = av.w;
    int k  = t >> 4;
    int n4 = (t & 15) * 4;
    const float4 bv = *(const float4*)(Bm + (size_t)(kt + k) * ldb + bcoloff + n0 + n4);
    *(float4*)(Bs + k*68 + n4) = bv;
    __syncthreads();
    #pragma unroll
    for (int kk = 0; kk < 16; ++kk) {
      float4 a4 = *(const float4*)(As + kk*68 + ty*4);
      float4 b4 = *(const float4*)(Bs + kk*68 + tx*4);
      float av_[4] = {a4.x, a4.y, a4.z, a4.w};
      float bv_[4] = {b4.x, b4.y, b4.z, b4.w};
      #pragma unroll
      for (int i = 0; i < 4; ++i)
        #pragma unroll
        for (int j = 0; j < 4; ++j)
          acc[i][j] = fmaf(av_[i], bv_[j], acc[i][j]);
    }
    __syncthreads();
  }

  #pragma unroll
  for (int i = 0; i < 4; ++i) {
    int r = m0 + ty*4 + i;
    int b = r >> 11, n = r & (NQ - 1);
    #pragma unroll
    for (int j = 0; j < 4; ++j) {
      int cc = n0 + tx*4 + j;
      if (MODE == 0) {
        C0[(size_t)r * N + cc] = acc[i][j] + bias[cc];
      } else {
        int h = cc >> 6, d = cc & 63;
        C0[(((size_t)(b*NHEADS + h))*NK + n)*64 + d] = acc[i][j];
      }
    }
  }
}

// ---------------------------------------------------------------------------
// Score GEMM via bf16x3 MFMA -> f16 scores (halves S traffic).
// ---------------------------------------------------------------------------
__global__ __launch_bounds__(256) void score_mfma(
    const unsigned short* __restrict__ Qhi, const unsigned short* __restrict__ Qlo,
    const unsigned short* __restrict__ Khi, const unsigned short* __restrict__ Klo,
    unsigned short* __restrict__ S16, int bh0)
{
  extern __shared__ unsigned short sm[];
  unsigned short* qh = sm;              // 128*72
  unsigned short* ql = qh + 128*72;
  unsigned short* kh = ql + 128*72;
  unsigned short* kl = kh + 128*72;     // total 73,728 B

  const int t  = threadIdx.x;
  const int qt = blockIdx.x, kt = blockIdx.y;
  const int bh = bh0 + blockIdx.z;
  const size_t qbase = ((size_t)bh*NQ + qt*128) * 64;
  const size_t kbase = ((size_t)bh*NK + kt*128) * 64;

  #pragma unroll
  for (int i = 0; i < 4; ++i) {
    int c   = t + i*256;        // chunk 0..1023 (16 B each)
    int row = c >> 3, off = (c & 7) * 8;
    *(u16x8*)(qh + row*72 + off) = *(const u16x8*)(Qhi + qbase + row*64 + off);
    *(u16x8*)(ql + row*72 + off) = *(const u16x8*)(Qlo + qbase + row*64 + off);
    *(u16x8*)(kh + row*72 + off) = *(const u16x8*)(Khi + kbase + row*64 + off);
    *(u16x8*)(kl + row*72 + off) = *(const u16x8*)(Klo + kbase + row*64 + off);
  }
  __syncthreads();

  const int w = t >> 6, l = t & 63;
  const int quad = l >> 4, lr = l & 15;

  frag_ab aH[2][2], aL[2][2];
  #pragma unroll
  for (int qs = 0; qs < 2; ++qs) {
    int row = w*32 + qs*16 + lr;
    #pragma unroll
    for (int s = 0; s < 2; ++s) {
      aH[qs][s] = *(const frag_ab*)(qh + row*72 + s*32 + quad*8);
      aL[qs][s] = *(const frag_ab*)(ql + row*72 + s*32 + quad*8);
    }
  }

  for (int ks = 0; ks < 8; ++ks) {
    frag_ab bH[2], bL[2];
    int krow = ks*16 + lr;
    #pragma unroll
    for (int s = 0; s < 2; ++s) {
      bH[s] = *(const frag_ab*)(kh + krow*72 + s*32 + quad*8);
      bL[s] = *(const frag_ab*)(kl + krow*72 + s*32 + quad*8);
    }
    #pragma unroll
    for (int qs = 0; qs < 2; ++qs) {
      frag_cd c = {0.f, 0.f, 0.f, 0.f};
      #pragma unroll
      for (int s = 0; s < 2; ++s) {
        c = __builtin_amdgcn_mfma_f32_16x16x32_bf16(aH[qs][s], bH[s], c, 0, 0, 0);
        c = __builtin_amdgcn_mfma_f32_16x16x32_bf16(aH[qs][s], bL[s], c, 0, 0, 0);
        c = __builtin_amdgcn_mfma_f32_16x16x32_bf16(aL[qs][s], bH[s], c, 0, 0, 0);
      }
      int qrow = qt*128 + w*32 + qs*16 + quad*4;   // + i
      int kcol = kt*128 + ks*16 + lr;
      size_t base = ((size_t)blockIdx.z * NQ + qrow) * NK + kcol;
      #pragma unroll
      for (int i = 0; i < 4; ++i) {
        _Float16 h = (_Float16)(c[i] * 0.125f);
        S16[base + (size_t)i*NK] = __builtin_bit_cast(unsigned short, h);
      }
    }
  }
}

// ---------------------------------------------------------------------------
// Select: per wave one query row. Exact f16-bits kth via 16-iter binary
// search, margin collect (skth - 3e-3) -> cand/cnt. Margin covers bf16x3
// (~1e-4) + f16 rounding (~6e-4) score error; superset-safe.
// ---------------------------------------------------------------------------
__global__ __launch_bounds__(256) void select_rows(
    const unsigned short* __restrict__ S16, unsigned short* __restrict__ cand,
    int* __restrict__ cnt, const int* __restrict__ topkp, int row0)
{
  const int t = threadIdx.x;
  const int w = t >> 6, l = t & 63;
  const int rl = blockIdx.x * 4 + w;
  const size_t row = (size_t)row0 + rl;
  const unsigned short* Sr = S16 + (size_t)rl * NK;
  const unsigned long long lmask = (1ull << l) - 1ull;

  int kEff = *topkp;
  if (kEff > CAND_MAX) kEff = CAND_MAX;
  if (kEff < 1) kEff = 1;

  unsigned uv[32];
  #pragma unroll
  for (int c = 0; c < 32; ++c) {
    unsigned bb = Sr[c*64 + l];
    uv[c] = (bb & 0x8000u) ? (~bb & 0xFFFFu) : (bb | 0x8000u);
  }
  unsigned lo_ = 0u, hi_ = 0xFFFFu;
  while (lo_ < hi_) {
    unsigned mid = (lo_ + hi_ + 1u) >> 1;
    int c_ = 0;
    #pragma unroll
    for (int c = 0; c < 32; ++c) c_ += (uv[c] >= mid) ? 1 : 0;
    #pragma unroll
    for (int off = 32; off > 0; off >>= 1) c_ += __shfl_xor(c_, off);
    if (c_ >= kEff) lo_ = mid; else hi_ = mid - 1;
  }
  unsigned short sb = (lo_ & 0x8000u) ? (unsigned short)(lo_ & 0x7FFFu)
                                      : (unsigned short)(~lo_ & 0xFFFFu);
  float skth = (float)__builtin_bit_cast(_Float16, sb);
  float smarg = skth - 3e-3f;
  _Float16 hm = (_Float16)smarg;
  unsigned short mb = __builtin_bit_cast(unsigned short, hm);
  unsigned um = (mb & 0x8000u) ? (~(unsigned)mb & 0xFFFFu) : ((unsigned)mb | 0x8000u);

  int base = 0;
  for (int c = 0; c < 32; ++c) {
    bool pred = (uv[c] >= um);
    unsigned long long msk = __ballot(pred);
    if (pred) {
      int pos = base + __popcll(msk & lmask);
      if (pos < CAND_MAX) cand[row*CAND_MAX + pos] = (unsigned short)(c*64 + l);
    }
    base += __popcll(msk);
  }
  if (l == 0) cnt[row] = (base < CAND_MAX) ? base : CAND_MAX;
}

// ---------------------------------------------------------------------------
// Phase B: group-coalesced f64 re-score (compile-time unrolled for m<=64),
// exact u64 kth, delta-blend boundary, unconditional unrolled PV, write inner.
// ---------------------------------------------------------------------------
__global__ __launch_bounds__(256) void attn_phase_b(
    const double* __restrict__ Q64, const double* __restrict__ K64,
    const float* __restrict__ V32, const unsigned short* __restrict__ cand,
    const int* __restrict__ cnt, float* __restrict__ inner,
    const int* __restrict__ topkp)
{
  const int t = threadIdx.x;
  const int w = t >> 6, l = t & 63;
  const size_t row = (size_t)blockIdx.x * 4 + w;
  const int bh = (int)(row >> 11);
  const int q  = (int)(row & (NQ - 1));
  const unsigned long long lmask = (1ull << l) - 1ull;

  int kEff = *topkp;
  if (kEff > CAND_MAX) kEff = CAND_MAX;
  if (kEff < 1) kEff = 1;
  int m = cnt[row];
  if (kEff > m) kEff = m;

  const double* Kb = K64 + (size_t)bh * NK * 64;
  const float*  Vb = V32 + (size_t)bh * NK * 64;

  const int g = l >> 3, r = l & 7;   // group, rank-in-group
  double2 q2[4];
  #pragma unroll
  for (int i = 0; i < 4; ++i)
    q2[i] = *(const double2*)(Q64 + row*64 + i*16 + r*2);

  int ck[2];
  ck[0] = cand[row*CAND_MAX + l];
  ck[1] = cand[row*CAND_MAX + 64 + l];
  double cs[2] = {-INFINITY, -INFINITY};
  unsigned long long cu[2] = {0ull, 0ull};

  #define RESCORE_PASS(P, C)                                                  \
  {                                                                           \
    const int j = (P)*8 + g;                                                  \
    const bool valid = (j < m);                                               \
    int key = __shfl(ck[C], j & 63);                                          \
    const double* kp = Kb + (size_t)(valid ? key : 0) * 64;                   \
    double s0 = 0.0, s1 = 0.0;                                                \
    _Pragma("unroll")                                                         \
    for (int i = 0; i < 4; ++i) {                                             \
      double2 kv = *(const double2*)(kp + i*16 + r*2);                        \
      s0 = fma(kv.x, q2[i].x, s0);                                            \
      s1 = fma(kv.y, q2[i].y, s1);                                            \
    }                                                                         \
    double s = s0 + s1;                                                       \
    s += __shfl_xor(s, 1);                                                    \
    s += __shfl_xor(s, 2);                                                    \
    s += __shfl_xor(s, 4);                                                    \
    s *= 0.125;                                                               \
    double sc = __shfl(s, (l & 7) * 8);                                       \
    const int pp = (P) & 7;                                                   \
    if ((l >> 3) == pp && ((C)*64 + pp*8 + (l & 7)) < m) {                    \
      unsigned long long b = (unsigned long long)__double_as_longlong(sc);    \
      cs[C] = sc;                                                             \
      cu[C] = (b >> 63) ? ~b : (b | 0x8000000000000000ull);                   \
    }                                                                         \
  }

  if (m <= 64) {
    #pragma unroll
    for (int p = 0; p < 8; ++p) RESCORE_PASS(p, 0)
  } else {
    #pragma unroll
    for (int p = 0; p < 8; ++p) RESCORE_PASS(p, 0)
    #pragma unroll
    for (int p = 8; p < 16; ++p) RESCORE_PASS(p, 1)
  }
  #undef RESCORE_PASS

  // exact kth largest u64
  unsigned long long T = 0ull;
  if (m > 64) {
    for (int bit = 63; bit >= 0; --bit) {
      unsigned long long cT = T | (1ull << bit);
      int tot = __popcll(__ballot(cu[0] >= cT)) + __popcll(__ballot(cu[1] >= cT));
      if (tot >= kEff) T = cT;
    }
  } else {
    for (int bit = 63; bit >= 0; --bit) {
      unsigned long long cT = T | (1ull << bit);
      int tot = __popcll(__ballot(cu[0] >= cT));
      if (tot >= kEff) T = cT;
    }
  }
  double s_kth;
  { unsigned long long bb = (T >> 63) ? (T & 0x7FFFFFFFFFFFFFFFull) : ~T;
    s_kth = __longlong_as_double((long long)bb); }

  double nx = -INFINITY;
  #pragma unroll
  for (int c = 0; c < 2; ++c) { double v = (cu[c] < T) ? cs[c] : -INFINITY; nx = fmax(nx, v); }
  #pragma unroll
  for (int off = 32; off > 0; off >>= 1) nx = fmax(nx, __shfl_xor(nx, off));

  double smax = fmax(cs[0], cs[1]);
  #pragma unroll
  for (int off = 32; off > 0; off >>= 1) smax = fmax(smax, __shfl_xor(smax, off));

  const double DELTA = 5e-6;
  float wgt[2];
  if (!(s_kth - nx < 2.0*DELTA)) {
    int cgt = __popcll(__ballot(cu[0] > T)) + __popcll(__ballot(cu[1] > T));
    int nEq = kEff - cgt;
    int eqBase = 0;
    #pragma unroll
    for (int c = 0; c < 2; ++c) {
      bool eq = (cu[c] == T);
      unsigned long long eqm = __ballot(eq);
      int er = __popcll(eqm & lmask);
      bool sel = (cu[c] > T) || (eq && (eqBase + er) < nEq);
      eqBase += __popcll(eqm);
      wgt[c] = sel ? (float)exp(cs[c] - smax) : 0.f;
    }
  } else {
    double cmid = 0.5 * (s_kth + nx);
    #pragma unroll
    for (int c = 0; c < 2; ++c) {
      double mu = 0.5 + (cs[c] - cmid) / (2.0*DELTA);
      mu = fmin(1.0, fmax(0.0, mu));
      wgt[c] = (float)(mu * exp(cs[c] - smax));
    }
  }

  // PV: unconditional (wj=0 tail contributes nothing; key masked in-range so
  // gathered value is finite), unrolled x4 so loads hoist.
  float acc = 0.f, wsum = 0.f;
  const int mm = (m + 3) & ~3;
  for (int j0 = 0; j0 < mm; j0 += 4) {
    #pragma unroll
    for (int u = 0; u < 4; ++u) {
      int j = j0 + u;
      int c = j >> 6;
      float wj = __shfl(wgt[c], j & 63);
      int key = __shfl(ck[c], j & 63) & (NK - 1);
      wsum += wj;
      acc = fmaf(wj, Vb[(size_t)key*64 + l], acc);
    }
  }
  int b = bh >> 3, h = bh & 7;
  inner[((size_t)b*NQ + q)*INNER + h*DHEAD + l] = acc / wsum;
}

// ---------------------------------------------------------------------------
extern "C" void kernel_launch(void* const* d_in, const int* in_sizes, int n_in,
                              void* d_out, int out_size, void* d_ws, size_t ws_size,
                              hipStream_t stream)
{
  const float* x    = (const float*)d_in[0];
  const float* ctx  = (const float*)d_in[1];
  const float* Wq   = (const float*)d_in[2];
  const float* Wkv  = (const float*)d_in[3];
  const float* Wout = (const float*)d_in[4];
  const float* bout = (const float*)d_in[5];
  const int*   topk = (const int*)d_in[6];
  float* out = (float*)d_out;

  const size_t SZ = (size_t)BATCH * NHEADS * NQ * DHEAD;  // 4,194,304

  // ---- ws layout (fixed ~112.5 MB) + adaptive f16 score slab + aliasing ----
  size_t off = 0;
  char* base = (char*)d_ws;
  auto take = [&](size_t bytes) { char* r = base + off; off += (bytes + 255) & ~(size_t)255; return r; };
  double* Q64 = (double*)take(SZ * sizeof(double));                        // 32 MB
  double* K64 = (double*)take(SZ * sizeof(double));                        // 32 MB
  unsigned short* cand = (unsigned short*)take((size_t)NROWS * CAND_MAX * 2); // 16 MB
  int* cnt = (int*)take((size_t)NROWS * sizeof(int));                      // 256 KB
  unsigned short* Qhi = (unsigned short*)take(SZ * 2);                     // 8 MB
  unsigned short* Qlo = (unsigned short*)take(SZ * 2);                     // 8 MB
  unsigned short* Khi = (unsigned short*)take(SZ * 2);                     // 8 MB
  unsigned short* Klo = (unsigned short*)take(SZ * 2);                     // 8 MB
  unsigned short* S16 = (unsigned short*)(base + off);   // remainder: f16 score slab
  // Aliases (live only after score/select complete):
  float* V32   = (float*)Qhi;               // 16 MB over Qhi+Qlo
  float* inner = (float*)Khi;               // 16 MB over Khi+Klo

  const size_t per_bh = (size_t)NQ * NK * sizeof(unsigned short);  // 8 MB
  size_t avail = (ws_size > off) ? (ws_size - off) : 0;
  int bhchunk = (int)(avail / per_bh);
  if (bhchunk < 1)  bhchunk = 1;
  if (bhchunk > 32) bhchunk = 32;

  const int M = BATCH * NQ;  // 8192
  const int SCORE_LDS = 4 * 128 * 72 * (int)sizeof(unsigned short); // 73,728 B
  hipFuncSetAttribute(reinterpret_cast<const void*>(score_mfma),
                      hipFuncAttributeMaxDynamicSharedMemorySize, SCORE_LDS);

  gemm_f64_proj<<<dim3(INNER/64, M/64), 256, 0, stream>>>(x,   Wq,  INNER,   0, Q64, Qhi, Qlo);
  gemm_f64_proj<<<dim3(INNER/64, M/64), 256, 0, stream>>>(ctx, Wkv, 2*INNER, 0, K64, Khi, Klo);

  for (int c0 = 0; c0 < BATCH*NHEADS; c0 += bhchunk) {
    int cc = BATCH*NHEADS - c0; if (cc > bhchunk) cc = bhchunk;
    score_mfma<<<dim3(NQ/128, NK/128, cc), 256, SCORE_LDS, stream>>>(
        Qhi, Qlo, Khi, Klo, S16, c0);
    select_rows<<<dim3(cc*NQ/4), 256, 0, stream>>>(S16, cand, cnt, topk, c0*NQ);
  }

  // V32 overwrites Qhi/Qlo (dead), inner overwrites Khi/Klo (dead).
  gemm_f32<2><<<dim3(INNER/64, M/64), 256, 0, stream>>>(ctx, Wkv, 2*INNER, INNER, nullptr, V32, M, INNER, DQ);
  attn_phase_b<<<dim3(NROWS/4), 256, 0, stream>>>(Q64, K64, V32, cand, cnt, inner, topk);
  gemm_f32<0><<<dim3(DQ/64, M/64), 256, 0, stream>>>(inner, Wout, DQ, 0, bout, out, M, DQ, INNER);
}

// Round 12
// 1094.247 us; speedup vs baseline: 3.1405x; 1.2580x over previous
//
#include <hip/hip_runtime.h>
#include <math.h>

#define BATCH 4
#define NQ 2048
#define NK 2048
#define DQ 1024
#define NHEADS 8
#define DHEAD 64
#define INNER (NHEADS*DHEAD)     // 512
#define NROWS (BATCH*NHEADS*NQ)  // 65536
#define CAND_MAX 128

using frag_ab = __attribute__((ext_vector_type(8))) short;   // 8 bf16
using frag_cd = __attribute__((ext_vector_type(4))) float;   // 4 fp32
using u16x8   = __attribute__((ext_vector_type(8))) unsigned short;

static __device__ __forceinline__ unsigned short f32_to_bf16_rne(float f) {
  unsigned u = __float_as_uint(f);
  u += 0x7FFFu + ((u >> 16) & 1u);
  return (unsigned short)(u >> 16);
}

// trunc hi/lo split: f = hi + lo + eps, |eps| <= ~2^-17 |f|
static __device__ __forceinline__ void split_trunc(float f, unsigned short& h, unsigned short& l) {
  unsigned u = __float_as_uint(f);
  h = (unsigned short)(u >> 16);
  float hf = __uint_as_float(u & 0xFFFF0000u);
  unsigned r = __float_as_uint(f - hf);
  l = (unsigned short)(r >> 16);
}

// ---------------------------------------------------------------------------
// f64-accumulate projection GEMM, f32 LDS staging (conflict-free).
// C64[bh][n][d] scatter + bf16 hi/lo split epilogue.
// ---------------------------------------------------------------------------
__global__ __launch_bounds__(256) void gemm_f64_proj(
    const float* __restrict__ A, const float* __restrict__ Bm,
    int ldb, int bcoloff, double* __restrict__ C64,
    unsigned short* __restrict__ Hi, unsigned short* __restrict__ Lo)
{
  __shared__ float As[16*68];  // [k][m]
  __shared__ float Bs[16*68];  // [k][n]
  const int t  = threadIdx.x;
  const int tx = t & 15, ty = t >> 4;
  const int n0 = blockIdx.x * 64, m0 = blockIdx.y * 64;
  double acc[4][4] = {};

  for (int kt = 0; kt < DQ; kt += 16) {
    {
      int m  = t >> 2;
      int c4 = (t & 3) * 4;
      const float4 av = *(const float4*)(A + (size_t)(m0 + m) * DQ + kt + c4);
      As[(c4+0)*68 + m] = av.x;
      As[(c4+1)*68 + m] = av.y;
      As[(c4+2)*68 + m] = av.z;
      As[(c4+3)*68 + m] = av.w;
      int k  = t >> 4;
      int n4 = (t & 15) * 4;
      const float4 bv = *(const float4*)(Bm + (size_t)(kt + k) * ldb + bcoloff + n0 + n4);
      *(float4*)(Bs + k*68 + n4) = bv;
    }
    __syncthreads();
    #pragma unroll
    for (int kk = 0; kk < 16; ++kk) {
      float4 a4 = *(const float4*)(As + kk*68 + ty*4);
      float4 b4 = *(const float4*)(Bs + kk*68 + tx*4);
      double ad[4] = {(double)a4.x, (double)a4.y, (double)a4.z, (double)a4.w};
      double bd[4] = {(double)b4.x, (double)b4.y, (double)b4.z, (double)b4.w};
      #pragma unroll
      for (int i = 0; i < 4; ++i)
        #pragma unroll
        for (int j = 0; j < 4; ++j)
          acc[i][j] = fma(ad[i], bd[j], acc[i][j]);
    }
    __syncthreads();
  }

  #pragma unroll
  for (int i = 0; i < 4; ++i) {
    int r = m0 + ty*4 + i;
    int b = r >> 11, n = r & (NQ - 1);
    #pragma unroll
    for (int j = 0; j < 4; ++j) {
      int cc = n0 + tx*4 + j;
      int h = cc >> 6, d = cc & 63;
      size_t idx = (((size_t)(b*NHEADS + h))*NQ + n)*64 + d;
      double v = acc[i][j];
      C64[idx] = v;
      float vf = (float)v;
      unsigned short hb = f32_to_bf16_rne(vf);
      float hf = __uint_as_float((unsigned)hb << 16);
      unsigned short lb = f32_to_bf16_rne(vf - hf);
      Hi[idx] = hb;
      Lo[idx] = lb;
    }
  }
}

// ---------------------------------------------------------------------------
// Weight transpose+split: W[K][ldw] (col-offset) -> WtH/WtL [N][K] u16.
// ---------------------------------------------------------------------------
__global__ __launch_bounds__(256) void split_wT(
    const float* __restrict__ W, int ldw, int coloff, int K, int N,
    unsigned short* __restrict__ TH, unsigned short* __restrict__ TL)
{
  __shared__ float tile[32*33];
  const int k0 = blockIdx.x * 32, n0 = blockIdx.y * 32;
  const int t = threadIdx.x;
  {
    int lk = t >> 3, ln4 = (t & 7) * 4;
    const float4 v = *(const float4*)(W + (size_t)(k0 + lk)*ldw + coloff + n0 + ln4);
    tile[lk*33 + ln4+0] = v.x;
    tile[lk*33 + ln4+1] = v.y;
    tile[lk*33 + ln4+2] = v.z;
    tile[lk*33 + ln4+3] = v.w;
  }
  __syncthreads();
  int n = t >> 3, k4 = (t & 7) * 4;
  #pragma unroll
  for (int j = 0; j < 4; ++j) {
    unsigned short h, l;
    split_trunc(tile[(k4+j)*33 + n], h, l);
    TH[(size_t)(n0 + n)*K + k0 + k4 + j] = h;
    TL[(size_t)(n0 + n)*K + k0 + k4 + j] = l;
  }
}

// ---------------------------------------------------------------------------
// bf16x3 MFMA GEMM: C[M][N] = A[M][K](f32, split on the fly) @ Bt(pre-split
// [N][K] hi/lo u16).  Tile 128m x 64n, BK=64, 4 waves.
// MODE 0: +bias row-major; MODE 2: scatter V[bh][n][d].
// ---------------------------------------------------------------------------
template<int MODE>
__global__ __launch_bounds__(256) void gemm_mfma3(
    const float* __restrict__ A, int lda,
    const unsigned short* __restrict__ BtH, const unsigned short* __restrict__ BtL,
    int K, int N, const float* __restrict__ bias, float* __restrict__ C0)
{
  __shared__ unsigned short ah[128*72];
  __shared__ unsigned short al[128*72];
  __shared__ unsigned short bh2[64*72];
  __shared__ unsigned short bl2[64*72];
  const int t = threadIdx.x;
  const int w = t >> 6, l = t & 63;
  const int lr = l & 15, quad = l >> 4;
  const int n0 = blockIdx.x * 64, m0 = blockIdx.y * 128;

  frag_cd acc[2][4];
  #pragma unroll
  for (int ms = 0; ms < 2; ++ms)
    #pragma unroll
    for (int nt = 0; nt < 4; ++nt)
      acc[ms][nt] = (frag_cd){0.f, 0.f, 0.f, 0.f};

  for (int kt = 0; kt < K; kt += 64) {
    // stage A (split f32 -> hi/lo bf16)
    #pragma unroll
    for (int i = 0; i < 4; ++i) {
      int idx = i*256 + t;
      int row = idx >> 3, k8 = (idx & 7) * 8;
      const float* src = A + (size_t)(m0 + row) * lda + kt + k8;
      float4 v0 = *(const float4*)(src);
      float4 v1 = *(const float4*)(src + 4);
      float vv[8] = {v0.x, v0.y, v0.z, v0.w, v1.x, v1.y, v1.z, v1.w};
      unsigned short h8[8], l8[8];
      #pragma unroll
      for (int j = 0; j < 8; ++j) split_trunc(vv[j], h8[j], l8[j]);
      *(u16x8*)(ah + row*72 + k8) = *(u16x8*)h8;
      *(u16x8*)(al + row*72 + k8) = *(u16x8*)l8;
    }
    // stage B (pre-split copy)
    #pragma unroll
    for (int i = 0; i < 2; ++i) {
      int idx = i*256 + t;
      int n = idx >> 3, k8 = (idx & 7) * 8;
      *(u16x8*)(bh2 + n*72 + k8) = *(const u16x8*)(BtH + (size_t)(n0 + n)*K + kt + k8);
      *(u16x8*)(bl2 + n*72 + k8) = *(const u16x8*)(BtL + (size_t)(n0 + n)*K + kt + k8);
    }
    __syncthreads();
    #pragma unroll
    for (int ks = 0; ks < 2; ++ks) {
      frag_ab aH[2], aL[2], bH[4], bL[4];
      #pragma unroll
      for (int ms = 0; ms < 2; ++ms) {
        int row = w*32 + ms*16 + lr;
        aH[ms] = *(const frag_ab*)(ah + row*72 + ks*32 + quad*8);
        aL[ms] = *(const frag_ab*)(al + row*72 + ks*32 + quad*8);
      }
      #pragma unroll
      for (int nt = 0; nt < 4; ++nt) {
        int row = nt*16 + lr;
        bH[nt] = *(const frag_ab*)(bh2 + row*72 + ks*32 + quad*8);
        bL[nt] = *(const frag_ab*)(bl2 + row*72 + ks*32 + quad*8);
      }
      #pragma unroll
      for (int ms = 0; ms < 2; ++ms)
        #pragma unroll
        for (int nt = 0; nt < 4; ++nt) {
          acc[ms][nt] = __builtin_amdgcn_mfma_f32_16x16x32_bf16(aH[ms], bH[nt], acc[ms][nt], 0, 0, 0);
          acc[ms][nt] = __builtin_amdgcn_mfma_f32_16x16x32_bf16(aH[ms], bL[nt], acc[ms][nt], 0, 0, 0);
          acc[ms][nt] = __builtin_amdgcn_mfma_f32_16x16x32_bf16(aL[ms], bH[nt], acc[ms][nt], 0, 0, 0);
        }
    }
    __syncthreads();
  }

  #pragma unroll
  for (int ms = 0; ms < 2; ++ms)
    #pragma unroll
    for (int nt = 0; nt < 4; ++nt) {
      int cc = n0 + nt*16 + lr;
      #pragma unroll
      for (int i = 0; i < 4; ++i) {
        int r = m0 + w*32 + ms*16 + quad*4 + i;
        float v = acc[ms][nt][i];
        if (MODE == 0) {
          C0[(size_t)r * N + cc] = v + bias[cc];
        } else {
          int b = r >> 11, n = r & (NQ - 1);
          int h = cc >> 6, d = cc & 63;
          C0[(((size_t)(b*NHEADS + h))*NK + n)*64 + d] = v;
        }
      }
    }
}

// ---------------------------------------------------------------------------
// Score GEMM via bf16x3 MFMA -> f16 scores.
// ---------------------------------------------------------------------------
__global__ __launch_bounds__(256) void score_mfma(
    const unsigned short* __restrict__ Qhi, const unsigned short* __restrict__ Qlo,
    const unsigned short* __restrict__ Khi, const unsigned short* __restrict__ Klo,
    unsigned short* __restrict__ S16, int bh0)
{
  extern __shared__ unsigned short sm[];
  unsigned short* qh = sm;              // 128*72
  unsigned short* ql = qh + 128*72;
  unsigned short* kh = ql + 128*72;
  unsigned short* kl = kh + 128*72;     // total 73,728 B

  const int t  = threadIdx.x;
  const int qt = blockIdx.x, kt = blockIdx.y;
  const int bh = bh0 + blockIdx.z;
  const size_t qbase = ((size_t)bh*NQ + qt*128) * 64;
  const size_t kbase = ((size_t)bh*NK + kt*128) * 64;

  #pragma unroll
  for (int i = 0; i < 4; ++i) {
    int c   = t + i*256;
    int row = c >> 3, off = (c & 7) * 8;
    *(u16x8*)(qh + row*72 + off) = *(const u16x8*)(Qhi + qbase + row*64 + off);
    *(u16x8*)(ql + row*72 + off) = *(const u16x8*)(Qlo + qbase + row*64 + off);
    *(u16x8*)(kh + row*72 + off) = *(const u16x8*)(Khi + kbase + row*64 + off);
    *(u16x8*)(kl + row*72 + off) = *(const u16x8*)(Klo + kbase + row*64 + off);
  }
  __syncthreads();

  const int w = t >> 6, l = t & 63;
  const int quad = l >> 4, lr = l & 15;

  frag_ab aH[2][2], aL[2][2];
  #pragma unroll
  for (int qs = 0; qs < 2; ++qs) {
    int row = w*32 + qs*16 + lr;
    #pragma unroll
    for (int s = 0; s < 2; ++s) {
      aH[qs][s] = *(const frag_ab*)(qh + row*72 + s*32 + quad*8);
      aL[qs][s] = *(const frag_ab*)(ql + row*72 + s*32 + quad*8);
    }
  }

  for (int ks = 0; ks < 8; ++ks) {
    frag_ab bH[2], bL[2];
    int krow = ks*16 + lr;
    #pragma unroll
    for (int s = 0; s < 2; ++s) {
      bH[s] = *(const frag_ab*)(kh + krow*72 + s*32 + quad*8);
      bL[s] = *(const frag_ab*)(kl + krow*72 + s*32 + quad*8);
    }
    #pragma unroll
    for (int qs = 0; qs < 2; ++qs) {
      frag_cd c = {0.f, 0.f, 0.f, 0.f};
      #pragma unroll
      for (int s = 0; s < 2; ++s) {
        c = __builtin_amdgcn_mfma_f32_16x16x32_bf16(aH[qs][s], bH[s], c, 0, 0, 0);
        c = __builtin_amdgcn_mfma_f32_16x16x32_bf16(aH[qs][s], bL[s], c, 0, 0, 0);
        c = __builtin_amdgcn_mfma_f32_16x16x32_bf16(aL[qs][s], bH[s], c, 0, 0, 0);
      }
      int qrow = qt*128 + w*32 + qs*16 + quad*4;
      int kcol = kt*128 + ks*16 + lr;
      size_t base = ((size_t)blockIdx.z * NQ + qrow) * NK + kcol;
      #pragma unroll
      for (int i = 0; i < 4; ++i) {
        _Float16 h = (_Float16)(c[i] * 0.125f);
        S16[base + (size_t)i*NK] = __builtin_bit_cast(unsigned short, h);
      }
    }
  }
}

// ---------------------------------------------------------------------------
// Select: exact f16-bits kth via binary search, margin collect (skth - 3e-3).
// ---------------------------------------------------------------------------
__global__ __launch_bounds__(256) void select_rows(
    const unsigned short* __restrict__ S16, unsigned short* __restrict__ cand,
    int* __restrict__ cnt, const int* __restrict__ topkp, int row0)
{
  const int t = threadIdx.x;
  const int w = t >> 6, l = t & 63;
  const int rl = blockIdx.x * 4 + w;
  const size_t row = (size_t)row0 + rl;
  const unsigned short* Sr = S16 + (size_t)rl * NK;
  const unsigned long long lmask = (1ull << l) - 1ull;

  int kEff = *topkp;
  if (kEff > CAND_MAX) kEff = CAND_MAX;
  if (kEff < 1) kEff = 1;

  unsigned uv[32];
  #pragma unroll
  for (int c = 0; c < 32; ++c) {
    unsigned bb = Sr[c*64 + l];
    uv[c] = (bb & 0x8000u) ? (~bb & 0xFFFFu) : (bb | 0x8000u);
  }
  unsigned lo_ = 0u, hi_ = 0xFFFFu;
  while (lo_ < hi_) {
    unsigned mid = (lo_ + hi_ + 1u) >> 1;
    int c_ = 0;
    #pragma unroll
    for (int c = 0; c < 32; ++c) c_ += (uv[c] >= mid) ? 1 : 0;
    #pragma unroll
    for (int off = 32; off > 0; off >>= 1) c_ += __shfl_xor(c_, off);
    if (c_ >= kEff) lo_ = mid; else hi_ = mid - 1;
  }
  unsigned short sb = (lo_ & 0x8000u) ? (unsigned short)(lo_ & 0x7FFFu)
                                      : (unsigned short)(~lo_ & 0xFFFFu);
  float skth = (float)__builtin_bit_cast(_Float16, sb);
  float smarg = skth - 3e-3f;
  _Float16 hm = (_Float16)smarg;
  unsigned short mb = __builtin_bit_cast(unsigned short, hm);
  unsigned um = (mb & 0x8000u) ? (~(unsigned)mb & 0xFFFFu) : ((unsigned)mb | 0x8000u);

  int base = 0;
  for (int c = 0; c < 32; ++c) {
    bool pred = (uv[c] >= um);
    unsigned long long msk = __ballot(pred);
    if (pred) {
      int pos = base + __popcll(msk & lmask);
      if (pos < CAND_MAX) cand[row*CAND_MAX + pos] = (unsigned short)(c*64 + l);
    }
    base += __popcll(msk);
  }
  if (l == 0) cnt[row] = (base < CAND_MAX) ? base : CAND_MAX;
}

// ---------------------------------------------------------------------------
// Phase B: group-coalesced f64 re-score, exact u64 kth, delta-blend,
// unconditional unrolled PV, write inner.
// ---------------------------------------------------------------------------
__global__ __launch_bounds__(256) void attn_phase_b(
    const double* __restrict__ Q64, const double* __restrict__ K64,
    const float* __restrict__ V32, const unsigned short* __restrict__ cand,
    const int* __restrict__ cnt, float* __restrict__ inner,
    const int* __restrict__ topkp)
{
  const int t = threadIdx.x;
  const int w = t >> 6, l = t & 63;
  const size_t row = (size_t)blockIdx.x * 4 + w;
  const int bh = (int)(row >> 11);
  const int q  = (int)(row & (NQ - 1));
  const unsigned long long lmask = (1ull << l) - 1ull;

  int kEff = *topkp;
  if (kEff > CAND_MAX) kEff = CAND_MAX;
  if (kEff < 1) kEff = 1;
  int m = cnt[row];
  if (kEff > m) kEff = m;

  const double* Kb = K64 + (size_t)bh * NK * 64;
  const float*  Vb = V32 + (size_t)bh * NK * 64;

  const int g = l >> 3, r = l & 7;
  double2 q2[4];
  #pragma unroll
  for (int i = 0; i < 4; ++i)
    q2[i] = *(const double2*)(Q64 + row*64 + i*16 + r*2);

  int ck[2];
  ck[0] = cand[row*CAND_MAX + l];
  ck[1] = cand[row*CAND_MAX + 64 + l];
  double cs[2] = {-INFINITY, -INFINITY};
  unsigned long long cu[2] = {0ull, 0ull};

  #define RESCORE_PASS(P, C)                                                  \
  {                                                                           \
    const int j = (P)*8 + g;                                                  \
    const bool valid = (j < m);                                               \
    int key = __shfl(ck[C], j & 63);                                          \
    const double* kp = Kb + (size_t)(valid ? key : 0) * 64;                   \
    double s0 = 0.0, s1 = 0.0;                                                \
    _Pragma("unroll")                                                         \
    for (int i = 0; i < 4; ++i) {                                             \
      double2 kv = *(const double2*)(kp + i*16 + r*2);                        \
      s0 = fma(kv.x, q2[i].x, s0);                                            \
      s1 = fma(kv.y, q2[i].y, s1);                                            \
    }                                                                         \
    double s = s0 + s1;                                                       \
    s += __shfl_xor(s, 1);                                                    \
    s += __shfl_xor(s, 2);                                                    \
    s += __shfl_xor(s, 4);                                                    \
    s *= 0.125;                                                               \
    double sc = __shfl(s, (l & 7) * 8);                                       \
    const int pp = (P) & 7;                                                   \
    if ((l >> 3) == pp && ((C)*64 + pp*8 + (l & 7)) < m) {                    \
      unsigned long long b = (unsigned long long)__double_as_longlong(sc);    \
      cs[C] = sc;                                                             \
      cu[C] = (b >> 63) ? ~b : (b | 0x8000000000000000ull);                   \
    }                                                                         \
  }

  if (m <= 64) {
    #pragma unroll
    for (int p = 0; p < 8; ++p) RESCORE_PASS(p, 0)
  } else {
    #pragma unroll
    for (int p = 0; p < 8; ++p) RESCORE_PASS(p, 0)
    #pragma unroll
    for (int p = 8; p < 16; ++p) RESCORE_PASS(p, 1)
  }
  #undef RESCORE_PASS

  unsigned long long T = 0ull;
  if (m > 64) {
    for (int bit = 63; bit >= 0; --bit) {
      unsigned long long cT = T | (1ull << bit);
      int tot = __popcll(__ballot(cu[0] >= cT)) + __popcll(__ballot(cu[1] >= cT));
      if (tot >= kEff) T = cT;
    }
  } else {
    for (int bit = 63; bit >= 0; --bit) {
      unsigned long long cT = T | (1ull << bit);
      int tot = __popcll(__ballot(cu[0] >= cT));
      if (tot >= kEff) T = cT;
    }
  }
  double s_kth;
  { unsigned long long bb = (T >> 63) ? (T & 0x7FFFFFFFFFFFFFFFull) : ~T;
    s_kth = __longlong_as_double((long long)bb); }

  double nx = -INFINITY;
  #pragma unroll
  for (int c = 0; c < 2; ++c) { double v = (cu[c] < T) ? cs[c] : -INFINITY; nx = fmax(nx, v); }
  #pragma unroll
  for (int off = 32; off > 0; off >>= 1) nx = fmax(nx, __shfl_xor(nx, off));

  double smax = fmax(cs[0], cs[1]);
  #pragma unroll
  for (int off = 32; off > 0; off >>= 1) smax = fmax(smax, __shfl_xor(smax, off));

  const double DELTA = 5e-6;
  float wgt[2];
  if (!(s_kth - nx < 2.0*DELTA)) {
    int cgt = __popcll(__ballot(cu[0] > T)) + __popcll(__ballot(cu[1] > T));
    int nEq = kEff - cgt;
    int eqBase = 0;
    #pragma unroll
    for (int c = 0; c < 2; ++c) {
      bool eq = (cu[c] == T);
      unsigned long long eqm = __ballot(eq);
      int er = __popcll(eqm & lmask);
      bool sel = (cu[c] > T) || (eq && (eqBase + er) < nEq);
      eqBase += __popcll(eqm);
      wgt[c] = sel ? (float)exp(cs[c] - smax) : 0.f;
    }
  } else {
    double cmid = 0.5 * (s_kth + nx);
    #pragma unroll
    for (int c = 0; c < 2; ++c) {
      double mu = 0.5 + (cs[c] - cmid) / (2.0*DELTA);
      mu = fmin(1.0, fmax(0.0, mu));
      wgt[c] = (float)(mu * exp(cs[c] - smax));
    }
  }

  float acc = 0.f, wsum = 0.f;
  const int mm = (m + 3) & ~3;
  for (int j0 = 0; j0 < mm; j0 += 4) {
    #pragma unroll
    for (int u = 0; u < 4; ++u) {
      int j = j0 + u;
      int c = j >> 6;
      float wj = __shfl(wgt[c], j & 63);
      int key = __shfl(ck[c], j & 63) & (NK - 1);
      wsum += wj;
      acc = fmaf(wj, Vb[(size_t)key*64 + l], acc);
    }
  }
  int b = bh >> 3, h = bh & 7;
  inner[((size_t)b*NQ + q)*INNER + h*DHEAD + l] = acc / wsum;
}

// ---------------------------------------------------------------------------
extern "C" void kernel_launch(void* const* d_in, const int* in_sizes, int n_in,
                              void* d_out, int out_size, void* d_ws, size_t ws_size,
                              hipStream_t stream)
{
  const float* x    = (const float*)d_in[0];
  const float* ctx  = (const float*)d_in[1];
  const float* Wq   = (const float*)d_in[2];
  const float* Wkv  = (const float*)d_in[3];
  const float* Wout = (const float*)d_in[4];
  const float* bout = (const float*)d_in[5];
  const int*   topk = (const int*)d_in[6];
  float* out = (float*)d_out;

  const size_t SZ = (size_t)BATCH * NHEADS * NQ * DHEAD;  // 4,194,304

  // ---- ws layout (fixed ~116.5 MB) + adaptive f16 score slab + aliasing ----
  size_t off = 0;
  char* base = (char*)d_ws;
  auto take = [&](size_t bytes) { char* r = base + off; off += (bytes + 255) & ~(size_t)255; return r; };
  double* Q64 = (double*)take(SZ * sizeof(double));                        // 32 MB
  double* K64 = (double*)take(SZ * sizeof(double));                        // 32 MB
  unsigned short* cand = (unsigned short*)take((size_t)NROWS * CAND_MAX * 2); // 16 MB
  int* cnt = (int*)take((size_t)NROWS * sizeof(int));                      // 256 KB
  unsigned short* Qhi = (unsigned short*)take(SZ * 2);                     // 8 MB
  unsigned short* Qlo = (unsigned short*)take(SZ * 2);                     // 8 MB
  unsigned short* Khi = (unsigned short*)take(SZ * 2);                     // 8 MB
  unsigned short* Klo = (unsigned short*)take(SZ * 2);                     // 8 MB
  unsigned short* WvTH = (unsigned short*)take((size_t)INNER * DQ * 2);    // 1 MB
  unsigned short* WvTL = (unsigned short*)take((size_t)INNER * DQ * 2);    // 1 MB
  unsigned short* WoTH = (unsigned short*)take((size_t)DQ * INNER * 2);    // 1 MB
  unsigned short* WoTL = (unsigned short*)take((size_t)DQ * INNER * 2);    // 1 MB
  unsigned short* S16 = (unsigned short*)(base + off);   // remainder: f16 score slab
  // Aliases (live only after score/select complete):
  float* V32   = (float*)Qhi;               // 16 MB over Qhi+Qlo
  float* inner = (float*)Khi;               // 16 MB over Khi+Klo

  const size_t per_bh = (size_t)NQ * NK * sizeof(unsigned short);  // 8 MB
  size_t avail = (ws_size > off) ? (ws_size - off) : 0;
  int bhchunk = (int)(avail / per_bh);
  if (bhchunk < 1)  bhchunk = 1;
  if (bhchunk > 32) bhchunk = 32;

  const int M = BATCH * NQ;  // 8192
  const int SCORE_LDS = 4 * 128 * 72 * (int)sizeof(unsigned short); // 73,728 B
  hipFuncSetAttribute(reinterpret_cast<const void*>(score_mfma),
                      hipFuncAttributeMaxDynamicSharedMemorySize, SCORE_LDS);

  // Weight transpose+split (tiny)
  split_wT<<<dim3(DQ/32, INNER/32), 256, 0, stream>>>(Wkv, 2*INNER, INNER, DQ, INNER, WvTH, WvTL);
  split_wT<<<dim3(INNER/32, DQ/32), 256, 0, stream>>>(Wout, DQ, 0, INNER, DQ, WoTH, WoTL);

  gemm_f64_proj<<<dim3(INNER/64, M/64), 256, 0, stream>>>(x,   Wq,  INNER,   0, Q64, Qhi, Qlo);
  gemm_f64_proj<<<dim3(INNER/64, M/64), 256, 0, stream>>>(ctx, Wkv, 2*INNER, 0, K64, Khi, Klo);

  for (int c0 = 0; c0 < BATCH*NHEADS; c0 += bhchunk) {
    int cc = BATCH*NHEADS - c0; if (cc > bhchunk) cc = bhchunk;
    score_mfma<<<dim3(NQ/128, NK/128, cc), 256, SCORE_LDS, stream>>>(
        Qhi, Qlo, Khi, Klo, S16, c0);
    select_rows<<<dim3(cc*NQ/4), 256, 0, stream>>>(S16, cand, cnt, topk, c0*NQ);
  }

  // V32 overwrites Qhi/Qlo (dead), inner overwrites Khi/Klo (dead).
  gemm_mfma3<2><<<dim3(INNER/64, M/128), 256, 0, stream>>>(ctx, DQ, WvTH, WvTL, DQ, INNER, nullptr, V32);
  attn_phase_b<<<dim3(NROWS/4), 256, 0, stream>>>(Q64, K64, V32, cand, cnt, inner, topk);
  gemm_mfma3<0><<<dim3(DQ/64, M/128), 256, 0, stream>>>(inner, INNER, WoTH, WoTL, INNER, DQ, bout, out);
}

// Round 13
// 956.614 us; speedup vs baseline: 3.5923x; 1.1439x over previous
//
#include <hip/hip_runtime.h>
#include <math.h>

#define BATCH 4
#define NQ 2048
#define NK 2048
#define DQ 1024
#define NHEADS 8
#define DHEAD 64
#define INNER (NHEADS*DHEAD)     // 512
#define NROWS (BATCH*NHEADS*NQ)  // 65536
#define CAND_MAX 128

using frag_ab = __attribute__((ext_vector_type(8))) short;   // 8 bf16
using frag_cd = __attribute__((ext_vector_type(4))) float;   // 4 fp32
using u16x8   = __attribute__((ext_vector_type(8))) unsigned short;

static __device__ __forceinline__ unsigned short f32_to_bf16_rne(float f) {
  unsigned u = __float_as_uint(f);
  u += 0x7FFFu + ((u >> 16) & 1u);
  return (unsigned short)(u >> 16);
}

// 2-way trunc split (for smooth-path mfma3): f ~ hi + lo, err ~2^-17|f|
static __device__ __forceinline__ void split_trunc(float f, unsigned short& h, unsigned short& l) {
  unsigned u = __float_as_uint(f);
  h = (unsigned short)(u >> 16);
  float hf = __uint_as_float(u & 0xFFFF0000u);
  unsigned r = __float_as_uint(f - hf);
  l = (unsigned short)(r >> 16);
}

// 3-way trunc split: f = hi + mid + lo EXACTLY (8+8+8 mantissa bits)
static __device__ __forceinline__ void split3(float f, unsigned short& h,
                                              unsigned short& m, unsigned short& l) {
  unsigned u = __float_as_uint(f);
  h = (unsigned short)(u >> 16);
  float hf = __uint_as_float(u & 0xFFFF0000u);
  float r1 = f - hf;                       // exact
  unsigned u1 = __float_as_uint(r1);
  m = (unsigned short)(u1 >> 16);
  float mf = __uint_as_float(u1 & 0xFFFF0000u);
  float r2 = r1 - mf;                      // exact, <=8 mantissa bits
  l = (unsigned short)(__float_as_uint(r2) >> 16);
}

// ---------------------------------------------------------------------------
// Weight transpose + 3-way split: W[K][ldw] (coloff) -> TH/TM/TL [N][K] u16.
// ---------------------------------------------------------------------------
__global__ __launch_bounds__(256) void split_wT3(
    const float* __restrict__ W, int ldw, int coloff, int K, int N,
    unsigned short* __restrict__ TH, unsigned short* __restrict__ TM,
    unsigned short* __restrict__ TL)
{
  __shared__ float tile[32*33];
  const int k0 = blockIdx.x * 32, n0 = blockIdx.y * 32;
  const int t = threadIdx.x;
  {
    int lk = t >> 3, ln4 = (t & 7) * 4;
    const float4 v = *(const float4*)(W + (size_t)(k0 + lk)*ldw + coloff + n0 + ln4);
    tile[lk*33 + ln4+0] = v.x;
    tile[lk*33 + ln4+1] = v.y;
    tile[lk*33 + ln4+2] = v.z;
    tile[lk*33 + ln4+3] = v.w;
  }
  __syncthreads();
  int n = t >> 3, k4 = (t & 7) * 4;
  #pragma unroll
  for (int j = 0; j < 4; ++j) {
    unsigned short h, m, l;
    split3(tile[(k4+j)*33 + n], h, m, l);
    size_t o = (size_t)(n0 + n)*K + k0 + k4 + j;
    TH[o] = h; TM[o] = m; TL[o] = l;
  }
}

// ---------------------------------------------------------------------------
// Weight transpose + 2-way split (smooth path).
// ---------------------------------------------------------------------------
__global__ __launch_bounds__(256) void split_wT(
    const float* __restrict__ W, int ldw, int coloff, int K, int N,
    unsigned short* __restrict__ TH, unsigned short* __restrict__ TL)
{
  __shared__ float tile[32*33];
  const int k0 = blockIdx.x * 32, n0 = blockIdx.y * 32;
  const int t = threadIdx.x;
  {
    int lk = t >> 3, ln4 = (t & 7) * 4;
    const float4 v = *(const float4*)(W + (size_t)(k0 + lk)*ldw + coloff + n0 + ln4);
    tile[lk*33 + ln4+0] = v.x;
    tile[lk*33 + ln4+1] = v.y;
    tile[lk*33 + ln4+2] = v.z;
    tile[lk*33 + ln4+3] = v.w;
  }
  __syncthreads();
  int n = t >> 3, k4 = (t & 7) * 4;
  #pragma unroll
  for (int j = 0; j < 4; ++j) {
    unsigned short h, l;
    split_trunc(tile[(k4+j)*33 + n], h, l);
    TH[(size_t)(n0 + n)*K + k0 + k4 + j] = h;
    TL[(size_t)(n0 + n)*K + k0 + k4 + j] = l;
  }
}

// ---------------------------------------------------------------------------
// 6-product bf16 MFMA projection GEMM (selection path, ~1e-6 abs err):
// C = A[M][1024](f32, 3-split on the fly) @ Bt(pre-3-split [512][1024]).
// Tile 128m x 128n, BK=64, 4 waves. Epilogue: C64 f64 scatter + RNE hi/lo.
// ---------------------------------------------------------------------------
__global__ __launch_bounds__(256) void gemm_mfma6_proj(
    const float* __restrict__ A,
    const unsigned short* __restrict__ BtH, const unsigned short* __restrict__ BtM,
    const unsigned short* __restrict__ BtL,
    double* __restrict__ C64,
    unsigned short* __restrict__ Hi, unsigned short* __restrict__ Lo)
{
  extern __shared__ unsigned short smp[];
  unsigned short* ah = smp;            // 128*72 each
  unsigned short* am = ah + 128*72;
  unsigned short* al = am + 128*72;
  unsigned short* bh = al + 128*72;
  unsigned short* bm = bh + 128*72;
  unsigned short* bl = bm + 128*72;    // total 110,592 B

  const int t = threadIdx.x;
  const int w = t >> 6, l = t & 63;
  const int lr = l & 15, quad = l >> 4;
  const int n0 = blockIdx.x * 128, m0 = blockIdx.y * 128;

  frag_cd acc[2][8];
  #pragma unroll
  for (int ms = 0; ms < 2; ++ms)
    #pragma unroll
    for (int nt = 0; nt < 8; ++nt)
      acc[ms][nt] = (frag_cd){0.f, 0.f, 0.f, 0.f};

  for (int kt = 0; kt < DQ; kt += 64) {
    // stage A: 128x64 f32 -> 3-way split
    #pragma unroll
    for (int i = 0; i < 4; ++i) {
      int idx = i*256 + t;
      int row = idx >> 3, k8 = (idx & 7) * 8;
      const float* src = A + (size_t)(m0 + row) * DQ + kt + k8;
      float4 v0 = *(const float4*)(src);
      float4 v1 = *(const float4*)(src + 4);
      float vv[8] = {v0.x, v0.y, v0.z, v0.w, v1.x, v1.y, v1.z, v1.w};
      unsigned short h8[8], m8[8], l8[8];
      #pragma unroll
      for (int j = 0; j < 8; ++j) split3(vv[j], h8[j], m8[j], l8[j]);
      *(u16x8*)(ah + row*72 + k8) = *(u16x8*)h8;
      *(u16x8*)(am + row*72 + k8) = *(u16x8*)m8;
      *(u16x8*)(al + row*72 + k8) = *(u16x8*)l8;
    }
    // stage B: 128x64 pre-split copies
    #pragma unroll
    for (int i = 0; i < 4; ++i) {
      int idx = i*256 + t;
      int n = idx >> 3, k8 = (idx & 7) * 8;
      size_t o = (size_t)(n0 + n)*DQ + kt + k8;
      *(u16x8*)(bh + n*72 + k8) = *(const u16x8*)(BtH + o);
      *(u16x8*)(bm + n*72 + k8) = *(const u16x8*)(BtM + o);
      *(u16x8*)(bl + n*72 + k8) = *(const u16x8*)(BtL + o);
    }
    __syncthreads();
    #pragma unroll
    for (int ks = 0; ks < 2; ++ks) {
      frag_ab aH[2], aM[2], aL[2];
      #pragma unroll
      for (int ms = 0; ms < 2; ++ms) {
        int row = w*32 + ms*16 + lr;
        aH[ms] = *(const frag_ab*)(ah + row*72 + ks*32 + quad*8);
        aM[ms] = *(const frag_ab*)(am + row*72 + ks*32 + quad*8);
        aL[ms] = *(const frag_ab*)(al + row*72 + ks*32 + quad*8);
      }
      #pragma unroll
      for (int nt = 0; nt < 8; ++nt) {
        int bn = nt*16 + lr;
        frag_ab bH_ = *(const frag_ab*)(bh + bn*72 + ks*32 + quad*8);
        frag_ab bM_ = *(const frag_ab*)(bm + bn*72 + ks*32 + quad*8);
        frag_ab bL_ = *(const frag_ab*)(bl + bn*72 + ks*32 + quad*8);
        #pragma unroll
        for (int ms = 0; ms < 2; ++ms) {
          frag_cd c = acc[ms][nt];
          // small terms first to reduce rounding
          c = __builtin_amdgcn_mfma_f32_16x16x32_bf16(aL[ms], bH_, c, 0, 0, 0);
          c = __builtin_amdgcn_mfma_f32_16x16x32_bf16(aH[ms], bL_, c, 0, 0, 0);
          c = __builtin_amdgcn_mfma_f32_16x16x32_bf16(aM[ms], bM_, c, 0, 0, 0);
          c = __builtin_amdgcn_mfma_f32_16x16x32_bf16(aM[ms], bH_, c, 0, 0, 0);
          c = __builtin_amdgcn_mfma_f32_16x16x32_bf16(aH[ms], bM_, c, 0, 0, 0);
          c = __builtin_amdgcn_mfma_f32_16x16x32_bf16(aH[ms], bH_, c, 0, 0, 0);
          acc[ms][nt] = c;
        }
      }
    }
    __syncthreads();
  }

  #pragma unroll
  for (int ms = 0; ms < 2; ++ms)
    #pragma unroll
    for (int nt = 0; nt < 8; ++nt) {
      int cc = n0 + nt*16 + lr;
      int h = cc >> 6, d = cc & 63;
      #pragma unroll
      for (int i = 0; i < 4; ++i) {
        int r = m0 + w*32 + ms*16 + quad*4 + i;
        int b = r >> 11, n = r & (NQ - 1);
        size_t idx = (((size_t)(b*NHEADS + h))*NQ + n)*64 + d;
        float vf = acc[ms][nt][i];
        C64[idx] = (double)vf;
        unsigned short hb = f32_to_bf16_rne(vf);
        float hf = __uint_as_float((unsigned)hb << 16);
        unsigned short lb = f32_to_bf16_rne(vf - hf);
        Hi[idx] = hb;
        Lo[idx] = lb;
      }
    }
}

// ---------------------------------------------------------------------------
// bf16x3 MFMA GEMM (smooth path). Tile 128m x 64n, BK=64.
// MODE 0: +bias row-major; MODE 2: scatter V[bh][n][d].
// ---------------------------------------------------------------------------
template<int MODE>
__global__ __launch_bounds__(256) void gemm_mfma3(
    const float* __restrict__ A, int lda,
    const unsigned short* __restrict__ BtH, const unsigned short* __restrict__ BtL,
    int K, int N, const float* __restrict__ bias, float* __restrict__ C0)
{
  __shared__ unsigned short ah[128*72];
  __shared__ unsigned short al[128*72];
  __shared__ unsigned short bh2[64*72];
  __shared__ unsigned short bl2[64*72];
  const int t = threadIdx.x;
  const int w = t >> 6, l = t & 63;
  const int lr = l & 15, quad = l >> 4;
  const int n0 = blockIdx.x * 64, m0 = blockIdx.y * 128;

  frag_cd acc[2][4];
  #pragma unroll
  for (int ms = 0; ms < 2; ++ms)
    #pragma unroll
    for (int nt = 0; nt < 4; ++nt)
      acc[ms][nt] = (frag_cd){0.f, 0.f, 0.f, 0.f};

  for (int kt = 0; kt < K; kt += 64) {
    #pragma unroll
    for (int i = 0; i < 4; ++i) {
      int idx = i*256 + t;
      int row = idx >> 3, k8 = (idx & 7) * 8;
      const float* src = A + (size_t)(m0 + row) * lda + kt + k8;
      float4 v0 = *(const float4*)(src);
      float4 v1 = *(const float4*)(src + 4);
      float vv[8] = {v0.x, v0.y, v0.z, v0.w, v1.x, v1.y, v1.z, v1.w};
      unsigned short h8[8], l8[8];
      #pragma unroll
      for (int j = 0; j < 8; ++j) split_trunc(vv[j], h8[j], l8[j]);
      *(u16x8*)(ah + row*72 + k8) = *(u16x8*)h8;
      *(u16x8*)(al + row*72 + k8) = *(u16x8*)l8;
    }
    #pragma unroll
    for (int i = 0; i < 2; ++i) {
      int idx = i*256 + t;
      int n = idx >> 3, k8 = (idx & 7) * 8;
      *(u16x8*)(bh2 + n*72 + k8) = *(const u16x8*)(BtH + (size_t)(n0 + n)*K + kt + k8);
      *(u16x8*)(bl2 + n*72 + k8) = *(const u16x8*)(BtL + (size_t)(n0 + n)*K + kt + k8);
    }
    __syncthreads();
    #pragma unroll
    for (int ks = 0; ks < 2; ++ks) {
      frag_ab aH[2], aL[2], bH[4], bL[4];
      #pragma unroll
      for (int ms = 0; ms < 2; ++ms) {
        int row = w*32 + ms*16 + lr;
        aH[ms] = *(const frag_ab*)(ah + row*72 + ks*32 + quad*8);
        aL[ms] = *(const frag_ab*)(al + row*72 + ks*32 + quad*8);
      }
      #pragma unroll
      for (int nt = 0; nt < 4; ++nt) {
        int row = nt*16 + lr;
        bH[nt] = *(const frag_ab*)(bh2 + row*72 + ks*32 + quad*8);
        bL[nt] = *(const frag_ab*)(bl2 + row*72 + ks*32 + quad*8);
      }
      #pragma unroll
      for (int ms = 0; ms < 2; ++ms)
        #pragma unroll
        for (int nt = 0; nt < 4; ++nt) {
          acc[ms][nt] = __builtin_amdgcn_mfma_f32_16x16x32_bf16(aH[ms], bH[nt], acc[ms][nt], 0, 0, 0);
          acc[ms][nt] = __builtin_amdgcn_mfma_f32_16x16x32_bf16(aH[ms], bL[nt], acc[ms][nt], 0, 0, 0);
          acc[ms][nt] = __builtin_amdgcn_mfma_f32_16x16x32_bf16(aL[ms], bH[nt], acc[ms][nt], 0, 0, 0);
        }
    }
    __syncthreads();
  }

  #pragma unroll
  for (int ms = 0; ms < 2; ++ms)
    #pragma unroll
    for (int nt = 0; nt < 4; ++nt) {
      int cc = n0 + nt*16 + lr;
      #pragma unroll
      for (int i = 0; i < 4; ++i) {
        int r = m0 + w*32 + ms*16 + quad*4 + i;
        float v = acc[ms][nt][i];
        if (MODE == 0) {
          C0[(size_t)r * N + cc] = v + bias[cc];
        } else {
          int b = r >> 11, n = r & (NQ - 1);
          int h = cc >> 6, d = cc & 63;
          C0[(((size_t)(b*NHEADS + h))*NK + n)*64 + d] = v;
        }
      }
    }
}

// ---------------------------------------------------------------------------
// Score GEMM via bf16x3 MFMA -> f16 scores.
// ---------------------------------------------------------------------------
__global__ __launch_bounds__(256) void score_mfma(
    const unsigned short* __restrict__ Qhi, const unsigned short* __restrict__ Qlo,
    const unsigned short* __restrict__ Khi, const unsigned short* __restrict__ Klo,
    unsigned short* __restrict__ S16, int bh0)
{
  extern __shared__ unsigned short sm[];
  unsigned short* qh = sm;              // 128*72
  unsigned short* ql = qh + 128*72;
  unsigned short* kh = ql + 128*72;
  unsigned short* kl = kh + 128*72;     // total 73,728 B

  const int t  = threadIdx.x;
  const int qt = blockIdx.x, kt = blockIdx.y;
  const int bh = bh0 + blockIdx.z;
  const size_t qbase = ((size_t)bh*NQ + qt*128) * 64;
  const size_t kbase = ((size_t)bh*NK + kt*128) * 64;

  #pragma unroll
  for (int i = 0; i < 4; ++i) {
    int c   = t + i*256;
    int row = c >> 3, off = (c & 7) * 8;
    *(u16x8*)(qh + row*72 + off) = *(const u16x8*)(Qhi + qbase + row*64 + off);
    *(u16x8*)(ql + row*72 + off) = *(const u16x8*)(Qlo + qbase + row*64 + off);
    *(u16x8*)(kh + row*72 + off) = *(const u16x8*)(Khi + kbase + row*64 + off);
    *(u16x8*)(kl + row*72 + off) = *(const u16x8*)(Klo + kbase + row*64 + off);
  }
  __syncthreads();

  const int w = t >> 6, l = t & 63;
  const int quad = l >> 4, lr = l & 15;

  frag_ab aH[2][2], aL[2][2];
  #pragma unroll
  for (int qs = 0; qs < 2; ++qs) {
    int row = w*32 + qs*16 + lr;
    #pragma unroll
    for (int s = 0; s < 2; ++s) {
      aH[qs][s] = *(const frag_ab*)(qh + row*72 + s*32 + quad*8);
      aL[qs][s] = *(const frag_ab*)(ql + row*72 + s*32 + quad*8);
    }
  }

  for (int ks = 0; ks < 8; ++ks) {
    frag_ab bH[2], bL[2];
    int krow = ks*16 + lr;
    #pragma unroll
    for (int s = 0; s < 2; ++s) {
      bH[s] = *(const frag_ab*)(kh + krow*72 + s*32 + quad*8);
      bL[s] = *(const frag_ab*)(kl + krow*72 + s*32 + quad*8);
    }
    #pragma unroll
    for (int qs = 0; qs < 2; ++qs) {
      frag_cd c = {0.f, 0.f, 0.f, 0.f};
      #pragma unroll
      for (int s = 0; s < 2; ++s) {
        c = __builtin_amdgcn_mfma_f32_16x16x32_bf16(aH[qs][s], bH[s], c, 0, 0, 0);
        c = __builtin_amdgcn_mfma_f32_16x16x32_bf16(aH[qs][s], bL[s], c, 0, 0, 0);
        c = __builtin_amdgcn_mfma_f32_16x16x32_bf16(aL[qs][s], bH[s], c, 0, 0, 0);
      }
      int qrow = qt*128 + w*32 + qs*16 + quad*4;
      int kcol = kt*128 + ks*16 + lr;
      size_t base = ((size_t)blockIdx.z * NQ + qrow) * NK + kcol;
      #pragma unroll
      for (int i = 0; i < 4; ++i) {
        _Float16 h = (_Float16)(c[i] * 0.125f);
        S16[base + (size_t)i*NK] = __builtin_bit_cast(unsigned short, h);
      }
    }
  }
}

// ---------------------------------------------------------------------------
// Select: exact f16-bits kth via binary search, margin collect (skth - 3e-3).
// ---------------------------------------------------------------------------
__global__ __launch_bounds__(256) void select_rows(
    const unsigned short* __restrict__ S16, unsigned short* __restrict__ cand,
    int* __restrict__ cnt, const int* __restrict__ topkp, int row0)
{
  const int t = threadIdx.x;
  const int w = t >> 6, l = t & 63;
  const int rl = blockIdx.x * 4 + w;
  const size_t row = (size_t)row0 + rl;
  const unsigned short* Sr = S16 + (size_t)rl * NK;
  const unsigned long long lmask = (1ull << l) - 1ull;

  int kEff = *topkp;
  if (kEff > CAND_MAX) kEff = CAND_MAX;
  if (kEff < 1) kEff = 1;

  unsigned uv[32];
  #pragma unroll
  for (int c = 0; c < 32; ++c) {
    unsigned bb = Sr[c*64 + l];
    uv[c] = (bb & 0x8000u) ? (~bb & 0xFFFFu) : (bb | 0x8000u);
  }
  unsigned lo_ = 0u, hi_ = 0xFFFFu;
  while (lo_ < hi_) {
    unsigned mid = (lo_ + hi_ + 1u) >> 1;
    int c_ = 0;
    #pragma unroll
    for (int c = 0; c < 32; ++c) c_ += (uv[c] >= mid) ? 1 : 0;
    #pragma unroll
    for (int off = 32; off > 0; off >>= 1) c_ += __shfl_xor(c_, off);
    if (c_ >= kEff) lo_ = mid; else hi_ = mid - 1;
  }
  unsigned short sb = (lo_ & 0x8000u) ? (unsigned short)(lo_ & 0x7FFFu)
                                      : (unsigned short)(~lo_ & 0xFFFFu);
  float skth = (float)__builtin_bit_cast(_Float16, sb);
  float smarg = skth - 3e-3f;
  _Float16 hm = (_Float16)smarg;
  unsigned short mb = __builtin_bit_cast(unsigned short, hm);
  unsigned um = (mb & 0x8000u) ? (~(unsigned)mb & 0xFFFFu) : ((unsigned)mb | 0x8000u);

  int base = 0;
  for (int c = 0; c < 32; ++c) {
    bool pred = (uv[c] >= um);
    unsigned long long msk = __ballot(pred);
    if (pred) {
      int pos = base + __popcll(msk & lmask);
      if (pos < CAND_MAX) cand[row*CAND_MAX + pos] = (unsigned short)(c*64 + l);
    }
    base += __popcll(msk);
  }
  if (l == 0) cnt[row] = (base < CAND_MAX) ? base : CAND_MAX;
}

// ---------------------------------------------------------------------------
// Phase B: group-coalesced f64 re-score, exact u64 kth, delta-blend,
// unconditional unrolled PV, write inner.
// ---------------------------------------------------------------------------
__global__ __launch_bounds__(256) void attn_phase_b(
    const double* __restrict__ Q64, const double* __restrict__ K64,
    const float* __restrict__ V32, const unsigned short* __restrict__ cand,
    const int* __restrict__ cnt, float* __restrict__ inner,
    const int* __restrict__ topkp)
{
  const int t = threadIdx.x;
  const int w = t >> 6, l = t & 63;
  const size_t row = (size_t)blockIdx.x * 4 + w;
  const int bh = (int)(row >> 11);
  const int q  = (int)(row & (NQ - 1));
  const unsigned long long lmask = (1ull << l) - 1ull;

  int kEff = *topkp;
  if (kEff > CAND_MAX) kEff = CAND_MAX;
  if (kEff < 1) kEff = 1;
  int m = cnt[row];
  if (kEff > m) kEff = m;

  const double* Kb = K64 + (size_t)bh * NK * 64;
  const float*  Vb = V32 + (size_t)bh * NK * 64;

  const int g = l >> 3, r = l & 7;
  double2 q2[4];
  #pragma unroll
  for (int i = 0; i < 4; ++i)
    q2[i] = *(const double2*)(Q64 + row*64 + i*16 + r*2);

  int ck[2];
  ck[0] = cand[row*CAND_MAX + l];
  ck[1] = cand[row*CAND_MAX + 64 + l];
  double cs[2] = {-INFINITY, -INFINITY};
  unsigned long long cu[2] = {0ull, 0ull};

  #define RESCORE_PASS(P, C)                                                  \
  {                                                                           \
    const int j = (P)*8 + g;                                                  \
    const bool valid = (j < m);                                               \
    int key = __shfl(ck[C], j & 63);                                          \
    const double* kp = Kb + (size_t)(valid ? key : 0) * 64;                   \
    double s0 = 0.0, s1 = 0.0;                                                \
    _Pragma("unroll")                                                         \
    for (int i = 0; i < 4; ++i) {                                             \
      double2 kv = *(const double2*)(kp + i*16 + r*2);                        \
      s0 = fma(kv.x, q2[i].x, s0);                                            \
      s1 = fma(kv.y, q2[i].y, s1);                                            \
    }                                                                         \
    double s = s0 + s1;                                                       \
    s += __shfl_xor(s, 1);                                                    \
    s += __shfl_xor(s, 2);                                                    \
    s += __shfl_xor(s, 4);                                                    \
    s *= 0.125;                                                               \
    double sc = __shfl(s, (l & 7) * 8);                                       \
    const int pp = (P) & 7;                                                   \
    if ((l >> 3) == pp && ((C)*64 + pp*8 + (l & 7)) < m) {                    \
      unsigned long long b = (unsigned long long)__double_as_longlong(sc);    \
      cs[C] = sc;                                                             \
      cu[C] = (b >> 63) ? ~b : (b | 0x8000000000000000ull);                   \
    }                                                                         \
  }

  if (m <= 64) {
    #pragma unroll
    for (int p = 0; p < 8; ++p) RESCORE_PASS(p, 0)
  } else {
    #pragma unroll
    for (int p = 0; p < 8; ++p) RESCORE_PASS(p, 0)
    #pragma unroll
    for (int p = 8; p < 16; ++p) RESCORE_PASS(p, 1)
  }
  #undef RESCORE_PASS

  unsigned long long T = 0ull;
  if (m > 64) {
    for (int bit = 63; bit >= 0; --bit) {
      unsigned long long cT = T | (1ull << bit);
      int tot = __popcll(__ballot(cu[0] >= cT)) + __popcll(__ballot(cu[1] >= cT));
      if (tot >= kEff) T = cT;
    }
  } else {
    for (int bit = 63; bit >= 0; --bit) {
      unsigned long long cT = T | (1ull << bit);
      int tot = __popcll(__ballot(cu[0] >= cT));
      if (tot >= kEff) T = cT;
    }
  }
  double s_kth;
  { unsigned long long bb = (T >> 63) ? (T & 0x7FFFFFFFFFFFFFFFull) : ~T;
    s_kth = __longlong_as_double((long long)bb); }

  double nx = -INFINITY;
  #pragma unroll
  for (int c = 0; c < 2; ++c) { double v = (cu[c] < T) ? cs[c] : -INFINITY; nx = fmax(nx, v); }
  #pragma unroll
  for (int off = 32; off > 0; off >>= 1) nx = fmax(nx, __shfl_xor(nx, off));

  double smax = fmax(cs[0], cs[1]);
  #pragma unroll
  for (int off = 32; off > 0; off >>= 1) smax = fmax(smax, __shfl_xor(smax, off));

  const double DELTA = 5e-6;
  float wgt[2];
  if (!(s_kth - nx < 2.0*DELTA)) {
    int cgt = __popcll(__ballot(cu[0] > T)) + __popcll(__ballot(cu[1] > T));
    int nEq = kEff - cgt;
    int eqBase = 0;
    #pragma unroll
    for (int c = 0; c < 2; ++c) {
      bool eq = (cu[c] == T);
      unsigned long long eqm = __ballot(eq);
      int er = __popcll(eqm & lmask);
      bool sel = (cu[c] > T) || (eq && (eqBase + er) < nEq);
      eqBase += __popcll(eqm);
      wgt[c] = sel ? (float)exp(cs[c] - smax) : 0.f;
    }
  } else {
    double cmid = 0.5 * (s_kth + nx);
    #pragma unroll
    for (int c = 0; c < 2; ++c) {
      double mu = 0.5 + (cs[c] - cmid) / (2.0*DELTA);
      mu = fmin(1.0, fmax(0.0, mu));
      wgt[c] = (float)(mu * exp(cs[c] - smax));
    }
  }

  float acc = 0.f, wsum = 0.f;
  const int mm = (m + 3) & ~3;
  for (int j0 = 0; j0 < mm; j0 += 4) {
    #pragma unroll
    for (int u = 0; u < 4; ++u) {
      int j = j0 + u;
      int c = j >> 6;
      float wj = __shfl(wgt[c], j & 63);
      int key = __shfl(ck[c], j & 63) & (NK - 1);
      wsum += wj;
      acc = fmaf(wj, Vb[(size_t)key*64 + l], acc);
    }
  }
  int b = bh >> 3, h = bh & 7;
  inner[((size_t)b*NQ + q)*INNER + h*DHEAD + l] = acc / wsum;
}

// ---------------------------------------------------------------------------
extern "C" void kernel_launch(void* const* d_in, const int* in_sizes, int n_in,
                              void* d_out, int out_size, void* d_ws, size_t ws_size,
                              hipStream_t stream)
{
  const float* x    = (const float*)d_in[0];
  const float* ctx  = (const float*)d_in[1];
  const float* Wq   = (const float*)d_in[2];
  const float* Wkv  = (const float*)d_in[3];
  const float* Wout = (const float*)d_in[4];
  const float* bout = (const float*)d_in[5];
  const int*   topk = (const int*)d_in[6];
  float* out = (float*)d_out;

  const size_t SZ = (size_t)BATCH * NHEADS * NQ * DHEAD;  // 4,194,304

  // ---- fixed ws region (112.5 MB, round-12-proven floor) ----
  size_t off = 0;
  char* base = (char*)d_ws;
  auto take = [&](size_t bytes) { char* r = base + off; off += (bytes + 255) & ~(size_t)255; return r; };
  double* Q64 = (double*)take(SZ * sizeof(double));                        // 32 MB
  double* K64 = (double*)take(SZ * sizeof(double));                        // 32 MB
  unsigned short* cand = (unsigned short*)take((size_t)NROWS * CAND_MAX * 2); // 16 MB
  int* cnt = (int*)take((size_t)NROWS * sizeof(int));                      // 256 KB
  unsigned short* Qhi = (unsigned short*)take(SZ * 2);                     // 8 MB
  unsigned short* Qlo = (unsigned short*)take(SZ * 2);                     // 8 MB
  unsigned short* Khi = (unsigned short*)take(SZ * 2);                     // 8 MB
  unsigned short* Klo = (unsigned short*)take(SZ * 2);                     // 8 MB
  char* slab = base + off;   // remainder (>= 8 MB): time-multiplexed region

  // slab phase 1 (before/during projections): Wq/Wk 3-way splits (6 MB)
  const size_t WSZ = (size_t)INNER * DQ * 2;   // 1 MB per split array
  unsigned short* WqTH = (unsigned short*)(slab + 0*WSZ);
  unsigned short* WqTM = (unsigned short*)(slab + 1*WSZ);
  unsigned short* WqTL = (unsigned short*)(slab + 2*WSZ);
  unsigned short* WkTH = (unsigned short*)(slab + 3*WSZ);
  unsigned short* WkTM = (unsigned short*)(slab + 4*WSZ);
  unsigned short* WkTL = (unsigned short*)(slab + 5*WSZ);
  // slab phase 2 (score/select): f16 score chunks
  unsigned short* S16 = (unsigned short*)slab;
  // slab phase 3 (after select): Wv/Wo 2-way splits (4 MB)
  unsigned short* WvTH = (unsigned short*)(slab + 0*WSZ);
  unsigned short* WvTL = (unsigned short*)(slab + 1*WSZ);
  unsigned short* WoTH = (unsigned short*)(slab + 2*WSZ);
  unsigned short* WoTL = (unsigned short*)(slab + 3*WSZ);
  // Aliases over fixed region (dead after score/select):
  float* V32   = (float*)Qhi;               // 16 MB over Qhi+Qlo
  float* inner = (float*)Khi;               // 16 MB over Khi+Klo

  const size_t per_bh = (size_t)NQ * NK * sizeof(unsigned short);  // 8 MB
  size_t avail = (ws_size > off) ? (ws_size - off) : 0;
  int bhchunk = (int)(avail / per_bh);
  if (bhchunk < 1)  bhchunk = 1;
  if (bhchunk > 32) bhchunk = 32;

  const int M = BATCH * NQ;  // 8192
  const int SCORE_LDS = 4 * 128 * 72 * (int)sizeof(unsigned short); // 73,728 B
  const int PROJ_LDS  = 6 * 128 * 72 * (int)sizeof(unsigned short); // 110,592 B
  hipFuncSetAttribute(reinterpret_cast<const void*>(score_mfma),
                      hipFuncAttributeMaxDynamicSharedMemorySize, SCORE_LDS);
  hipFuncSetAttribute(reinterpret_cast<const void*>(gemm_mfma6_proj),
                      hipFuncAttributeMaxDynamicSharedMemorySize, PROJ_LDS);

  // Wq / Wk(first half of Wkv) transpose + 3-way split
  split_wT3<<<dim3(DQ/32, INNER/32), 256, 0, stream>>>(Wq,  INNER,   0, DQ, INNER, WqTH, WqTM, WqTL);
  split_wT3<<<dim3(DQ/32, INNER/32), 256, 0, stream>>>(Wkv, 2*INNER, 0, DQ, INNER, WkTH, WkTM, WkTL);

  gemm_mfma6_proj<<<dim3(INNER/128, M/128), 256, PROJ_LDS, stream>>>(x,   WqTH, WqTM, WqTL, Q64, Qhi, Qlo);
  gemm_mfma6_proj<<<dim3(INNER/128, M/128), 256, PROJ_LDS, stream>>>(ctx, WkTH, WkTM, WkTL, K64, Khi, Klo);

  for (int c0 = 0; c0 < BATCH*NHEADS; c0 += bhchunk) {
    int cc = BATCH*NHEADS - c0; if (cc > bhchunk) cc = bhchunk;
    score_mfma<<<dim3(NQ/128, NK/128, cc), 256, SCORE_LDS, stream>>>(
        Qhi, Qlo, Khi, Klo, S16, c0);
    select_rows<<<dim3(cc*NQ/4), 256, 0, stream>>>(S16, cand, cnt, topk, c0*NQ);
  }

  // slab phase 3: Wv/Wo splits (S16 dead after last select)
  split_wT<<<dim3(DQ/32, INNER/32), 256, 0, stream>>>(Wkv, 2*INNER, INNER, DQ, INNER, WvTH, WvTL);
  split_wT<<<dim3(INNER/32, DQ/32), 256, 0, stream>>>(Wout, DQ, 0, INNER, DQ, WoTH, WoTL);

  // V32 overwrites Qhi/Qlo (dead), inner overwrites Khi/Klo (dead).
  gemm_mfma3<2><<<dim3(INNER/64, M/128), 256, 0, stream>>>(ctx, DQ, WvTH, WvTL, DQ, INNER, nullptr, V32);
  attn_phase_b<<<dim3(NROWS/4), 256, 0, stream>>>(Q64, K64, V32, cand, cnt, inner, topk);
  gemm_mfma3<0><<<dim3(DQ/64, M/128), 256, 0, stream>>>(inner, INNER, WoTH, WoTL, INNER, DQ, bout, out);
}